// Round 9
// baseline (72.187 us; speedup 1.0000x reference)
//
#include <hip/hip_runtime.h>

// Poisson composition via real DCT/DST algebra on matrix cores, single-fp16
// MFMA (f32 accumulate). 7 launches. Per-z operand LDS-staged (BK=64 dbuf);
// TABLE operand (Mc/Ms/McT/GT, frag-major) read from global (L2) into
// registers with one-step software prefetch. XCD-chunked block swizzle.
// Chain (TN GEMMs, C[m][n] = sum_k A[m][k]*Bt[n][k], fp16 operands):
//   d=s-t (nat->A, T->B; z==6 builds frag-major tables) ;
//   L1: gx=d~GT, gyT=dT~GT + mask(+T) -> uxT(C), uyT(D)
//   L2: P=Mc~uxT -> A, Q=Ms~uyT -> B
//   L3: GxT=Ms~P & GyT=Mc~Q + napply -> npT(C)
//   L4: R=McT~npT -> D ; L5: U=R~McT -> F0 (+ masked-dot partials)
//   final_out: out = t + U + shift[z].

#define CH 262144   // 512*512
#define NCH 6
#define NTOT (NCH*CH)

typedef _Float16 f16x8 __attribute__((ext_vector_type(8)));
typedef float f32x4  __attribute__((ext_vector_type(4)));

static constexpr float kPi        = 3.14159265358979323846f;
static constexpr float kPiOver512 = 0.006135923151542565f;   // pi/512
static constexpr float kPi2Norm   = 3.7649933338155804e-05f; // pi^2/512^2
static constexpr float kInvHW     = 3.814697265625e-06f;     // 1/512^2

__device__ __forceinline__ void hst(float v, short* p) {
    *reinterpret_cast<_Float16*>(p) = (_Float16)v;
}

__device__ __forceinline__ float hfun(int k) {
    if (k == 0) return 0.f;
    float sgn = 1.f;
    if (k < 0) { k = -k; sgn = -1.f; }
    if (k > 512) { k = 1024 - k; sgn = -sgn; }
    float sv, cv;
    sincosf((float)k * (kPi / 1024.0f), &sv, &cv);
    float v = cv / sv;
    if (k & 1) v = -v;
    return sgn * v;
}

// XCD-chunked swizzle (nwg % 8 == 0): XCD k owns logical chunk k*nwg/8 ..
__device__ __forceinline__ void xcd_remap(int& bx, int& by, int& bz) {
    int nx = gridDim.x, ny = gridDim.y;
    int nwg = nx * ny * gridDim.z;
    int w = blockIdx.x + nx * (blockIdx.y + ny * blockIdx.z);
    int s = (w & 7) * (nwg >> 3) + (w >> 3);
    bx = s % nx; s /= nx;
    by = s % ny;
    bz = s / ny;
}

// ---------------- GEMM machinery ----------------
__device__ __forceinline__ void gl_lds16(const short* g, const short* l) {
    __builtin_amdgcn_global_load_lds(
        (const __attribute__((address_space(1))) void*)g,
        (__attribute__((address_space(3))) void*)l, 16, 0, 0);
}

// X LDS tile: 64 rows x 64 k fp16 = 8 KB/buf. Row r slot s holds chunk s^(r&7).
#define FOFF(r, j) (((r) << 6) + 8 * ((j) ^ ((r) & 7)))
#define MFMA16(a, b, c) __builtin_amdgcn_mfma_f32_16x16x32_f16(a, b, c, 0, 0, 0)
// frag-major table: frag f = r_tile*16 + k_chunk at T[f*512 + lane*8]

// OM: 1 = fp16 out; 2 = fp32 C + masked-dot partials.
// TA: 1 = table is A-side (rows); 0 = table is B-side (cols).
template<int OM, int TA>
__global__ __launch_bounds__(256) void gemm_tn(
    const short* __restrict__ T0, const short* __restrict__ X0, int sX0,
    float* __restrict__ Cf0, short* __restrict__ O0, int sC0,
    const short* __restrict__ T1, const short* __restrict__ X1, int sX1,
    float* __restrict__ Cf1, short* __restrict__ O1, int sC1,
    int zsplit, const float* __restrict__ msk, float* __restrict__ redp)
{
    __shared__ short LS[2][4096];   // [buf][64x64 fp16 X tile]
    int bx, by, z;
    xcd_remap(bx, by, z);
    const short *T, *X; float* Cf; short* O;
    if (z < zsplit) {
        T = T0; X = X0 + (size_t)z * sX0;
        Cf = Cf0 ? Cf0 + (size_t)z * sC0 : nullptr;
        O  = O0 ? O0 + (size_t)z * sC0 : nullptr;
    } else {
        int zz = z - zsplit;
        T = T1; X = X1 + (size_t)zz * sX1;
        Cf = Cf1 ? Cf1 + (size_t)zz * sC1 : nullptr;
        O  = O1 ? O1 + (size_t)zz * sC1 : nullptr;
    }
    int tid = threadIdx.x;
    int l = tid & 63, w = tid >> 6;
    int m0 = by * 64, n0 = bx * 64;

    int xbase = TA ? n0 : m0;
    int srow = w * 8 + (l >> 3);
    int skc  = (l & 7) ^ ((l >> 3) & 7);
    const short* gX = X + (size_t)(xbase + srow) * 512 + 8 * skc;

    int wr = w >> 1, wc = w & 1;
    int lr = l & 15, lc = l >> 4;
    int rX0 = (TA ? wc : wr) * 32 + lr, rX1 = rX0 + 16;
    int ttb = (TA ? (m0 + wr * 32) : (n0 + wc * 32)) >> 4;
    const short* Tw0 = T + (size_t)ttb * 8192 + l * 8;
    const short* Tw1 = Tw0 + 8192;

    f32x4 a00 = {0,0,0,0}, a01 = a00, a10 = a00, a11 = a00;

#define STAGE_X(nb, k0) \
    gl_lds16(gX + (k0), &LS[nb][w * 512]); \
    gl_lds16(gX + (k0) + 32 * 512, &LS[nb][w * 512 + 2048]);

    STAGE_X(0, 0)
    // table frags for step 0 (kc = 0,1)
    f16x8 ct00 = *(const f16x8*)(Tw0);
    f16x8 ct01 = *(const f16x8*)(Tw0 + 512);
    f16x8 ct10 = *(const f16x8*)(Tw1);
    f16x8 ct11 = *(const f16x8*)(Tw1 + 512);
    __syncthreads();

#pragma unroll
    for (int step = 0; step < 8; ++step) {
        int buf = step & 1;
        f16x8 nt00, nt01, nt10, nt11;
        if (step < 7) {
            STAGE_X(buf ^ 1, (step + 1) * 64)
            const short* tn0 = Tw0 + (2 * step + 2) * 512;
            const short* tn1 = Tw1 + (2 * step + 2) * 512;
            nt00 = *(const f16x8*)(tn0);
            nt01 = *(const f16x8*)(tn0 + 512);
            nt10 = *(const f16x8*)(tn1);
            nt11 = *(const f16x8*)(tn1 + 512);
        }
        // ks = 0
        {
            f16x8 x0 = *(const f16x8*)&LS[buf][FOFF(rX0, lc)];
            f16x8 x1 = *(const f16x8*)&LS[buf][FOFF(rX1, lc)];
            if constexpr (TA) {
                a00 = MFMA16(ct00, x0, a00);
                a01 = MFMA16(ct00, x1, a01);
                a10 = MFMA16(ct10, x0, a10);
                a11 = MFMA16(ct10, x1, a11);
            } else {
                a00 = MFMA16(x0, ct00, a00);
                a01 = MFMA16(x0, ct10, a01);
                a10 = MFMA16(x1, ct00, a10);
                a11 = MFMA16(x1, ct10, a11);
            }
        }
        // ks = 1
        {
            f16x8 x0 = *(const f16x8*)&LS[buf][FOFF(rX0, lc + 4)];
            f16x8 x1 = *(const f16x8*)&LS[buf][FOFF(rX1, lc + 4)];
            if constexpr (TA) {
                a00 = MFMA16(ct01, x0, a00);
                a01 = MFMA16(ct01, x1, a01);
                a10 = MFMA16(ct11, x0, a10);
                a11 = MFMA16(ct11, x1, a11);
            } else {
                a00 = MFMA16(x0, ct01, a00);
                a01 = MFMA16(x0, ct11, a01);
                a10 = MFMA16(x1, ct01, a10);
                a11 = MFMA16(x1, ct11, a11);
            }
        }
        __syncthreads();
        if (step < 7) { ct00 = nt00; ct01 = nt01; ct10 = nt10; ct11 = nt11; }
    }
#undef STAGE_X

    // C layout: A-side rows -> crow. TA=1: rows from table (m0+wr...);
    // TA=0: rows from X (m0+wr...). Same formula either way.
    int crow = m0 + wr * 32 + lc * 4;
    int ccol = n0 + wc * 32 + lr;
    const f32x4* accs[2][2] = {{&a00, &a01}, {&a10, &a11}};
    float lsum = 0.f;
#pragma unroll
    for (int q = 0; q < 2; ++q)
#pragma unroll
        for (int pp = 0; pp < 2; ++pp)
#pragma unroll
            for (int rr = 0; rr < 4; ++rr) {
                int idx = (crow + q * 16 + rr) * 512 + ccol + pp * 16;
                float v = (*accs[q][pp])[rr];
                if (OM == 1) {
                    hst(v, O + idx);
                } else {
                    Cf[idx] = v;
                    lsum += v * (1.0f - msk[(size_t)z * CH + idx]);
                }
            }
    if (OM == 2) {
        float* red = (float*)LS;
        red[tid] = lsum;
        __syncthreads();
        for (int s2 = 128; s2 > 0; s2 >>= 1) {
            if (tid < s2) red[tid] += red[tid + s2];
            __syncthreads();
        }
        if (tid == 0) redp[z * 64 + by * 8 + bx] = red[0];
    }
}

// ---------------- L1 fused: gradients + mask + transpose ----------------
// A = d (staged), B = GT table (reg-prefetched).
__global__ __launch_bounds__(256) void gemm_l1(
    const short* __restrict__ dn, const short* __restrict__ dt,
    const short* __restrict__ GT, const float* __restrict__ msk,
    short* __restrict__ C_, short* __restrict__ D_)
{
    __shared__ short LS[2][4352];   // 17408 B; X uses [0..4096), tile reuse fits
    int bx, by, z;
    xcd_remap(bx, by, z);
    bool gxp = z < 6;
    int zz = gxp ? z : z - 6;
    const short* X = (gxp ? dn : dt) + (size_t)zz * CH;
    const float* mz = msk + (size_t)zz * CH;

    int tid = threadIdx.x;
    int l = tid & 63, w = tid >> 6;
    int m0 = by * 64, n0 = bx * 64;

    int srow = w * 8 + (l >> 3);
    int skc  = (l & 7) ^ ((l >> 3) & 7);
    const short* gX = X + (size_t)(m0 + srow) * 512 + 8 * skc;

    int wr = w >> 1, wc = w & 1;
    int lr = l & 15, lc = l >> 4;
    int rX0 = wr * 32 + lr, rX1 = rX0 + 16;
    int ttb = (n0 + wc * 32) >> 4;
    const short* Tw0 = GT + (size_t)ttb * 8192 + l * 8;
    const short* Tw1 = Tw0 + 8192;

    f32x4 a00 = {0,0,0,0}, a01 = a00, a10 = a00, a11 = a00;

#define STAGE_X(nb, k0) \
    gl_lds16(gX + (k0), &LS[nb][w * 512]); \
    gl_lds16(gX + (k0) + 32 * 512, &LS[nb][w * 512 + 2048]);

    STAGE_X(0, 0)
    f16x8 ct00 = *(const f16x8*)(Tw0);
    f16x8 ct01 = *(const f16x8*)(Tw0 + 512);
    f16x8 ct10 = *(const f16x8*)(Tw1);
    f16x8 ct11 = *(const f16x8*)(Tw1 + 512);
    __syncthreads();

#pragma unroll
    for (int step = 0; step < 8; ++step) {
        int buf = step & 1;
        f16x8 nt00, nt01, nt10, nt11;
        if (step < 7) {
            STAGE_X(buf ^ 1, (step + 1) * 64)
            const short* tn0 = Tw0 + (2 * step + 2) * 512;
            const short* tn1 = Tw1 + (2 * step + 2) * 512;
            nt00 = *(const f16x8*)(tn0);
            nt01 = *(const f16x8*)(tn0 + 512);
            nt10 = *(const f16x8*)(tn1);
            nt11 = *(const f16x8*)(tn1 + 512);
        }
        {
            f16x8 x0 = *(const f16x8*)&LS[buf][FOFF(rX0, lc)];
            f16x8 x1 = *(const f16x8*)&LS[buf][FOFF(rX1, lc)];
            a00 = MFMA16(x0, ct00, a00);
            a01 = MFMA16(x0, ct10, a01);
            a10 = MFMA16(x1, ct00, a10);
            a11 = MFMA16(x1, ct10, a11);
        }
        {
            f16x8 x0 = *(const f16x8*)&LS[buf][FOFF(rX0, lc + 4)];
            f16x8 x1 = *(const f16x8*)&LS[buf][FOFF(rX1, lc + 4)];
            a00 = MFMA16(x0, ct01, a00);
            a01 = MFMA16(x0, ct11, a01);
            a10 = MFMA16(x1, ct01, a10);
            a11 = MFMA16(x1, ct11, a11);
        }
        __syncthreads();
        if (step < 7) { ct00 = nt00; ct01 = nt01; ct10 = nt10; ct11 = nt11; }
    }
#undef STAGE_X

    const f32x4* accs[2][2] = {{&a00, &a01}, {&a10, &a11}};
    float* tile = (float*)LS;   // 64x65 floats = 16640 B <= 17408 B

    if (gxp) {
        short* o = C_ + (size_t)zz * CH;
#pragma unroll
        for (int q = 0; q < 2; ++q)
#pragma unroll
            for (int pp = 0; pp < 2; ++pp)
#pragma unroll
                for (int rr = 0; rr < 4; ++rr) {
                    int r = wr * 32 + lc * 4 + q * 16 + rr;
                    int c = wc * 32 + pp * 16 + lr;
                    float v = (*accs[q][pp])[rr] * mz[(size_t)(m0 + r) * 512 + n0 + c];
                    tile[c * 65 + r] = v;
                }
        __syncthreads();
#pragma unroll
        for (int pass = 0; pass < 16; ++pass) {
            int jj = pass * 4 + (tid >> 6);
            int ii = tid & 63;
            hst(tile[jj * 65 + ii], o + (n0 + jj) * 512 + m0 + ii);
        }
    } else {
        short* o = D_ + (size_t)zz * CH;
#pragma unroll
        for (int pass = 0; pass < 16; ++pass) {
            int ii = pass * 4 + (tid >> 6);
            int jj = tid & 63;
            tile[jj * 65 + ii] = mz[(size_t)(n0 + ii) * 512 + m0 + jj];
        }
        __syncthreads();
#pragma unroll
        for (int q = 0; q < 2; ++q)
#pragma unroll
            for (int pp = 0; pp < 2; ++pp)
#pragma unroll
                for (int rr = 0; rr < 4; ++rr) {
                    int r = wr * 32 + lc * 4 + q * 16 + rr;
                    int c = wc * 32 + pp * 16 + lr;
                    float v = (*accs[q][pp])[rr] * tile[r * 65 + c];
                    hst(v, o + (m0 + r) * 512 + n0 + c);
                }
    }
}

// ---------------- L3 fused: GxT & GyT + napply epilogue ----------------
// A = Ms/Mc tables (reg-prefetched), B = P,Q (staged).
__global__ __launch_bounds__(256) void gemm_l3(
    const short* __restrict__ Ms, const short* __restrict__ Mc,
    const short* __restrict__ P, const short* __restrict__ Q,
    short* __restrict__ O_)
{
    __shared__ short LS[2][2][4096];   // [buf][P,Q]
    int bx, by, z;
    xcd_remap(bx, by, z);
    const short* pz = P + (size_t)z * CH;
    const short* qz = Q + (size_t)z * CH;
    short* o = O_ + (size_t)z * CH;

    int tid = threadIdx.x;
    int l = tid & 63, w = tid >> 6;
    int m0 = by * 64, n0 = bx * 64;

    int srow = w * 8 + (l >> 3);
    int skc  = (l & 7) ^ ((l >> 3) & 7);
    const short* gP = pz + (size_t)(n0 + srow) * 512 + 8 * skc;
    const short* gQ = qz + (size_t)(n0 + srow) * 512 + 8 * skc;

    int wr = w >> 1, wc = w & 1;
    int lr = l & 15, lc = l >> 4;
    int rB0 = wc * 32 + lr, rB1 = rB0 + 16;
    int ttb = (m0 + wr * 32) >> 4;
    const short* Sw0 = Ms + (size_t)ttb * 8192 + l * 8;
    const short* Sw1 = Sw0 + 8192;
    const short* Cw0 = Mc + (size_t)ttb * 8192 + l * 8;
    const short* Cw1 = Cw0 + 8192;

    f32x4 x00 = {0,0,0,0}, x01 = x00, x10 = x00, x11 = x00;
    f32x4 y00 = x00, y01 = x00, y10 = x00, y11 = x00;

#define STAGE_PQ(nb, k0) \
    gl_lds16(gP + (k0), &LS[nb][0][w * 512]); \
    gl_lds16(gP + (k0) + 32 * 512, &LS[nb][0][w * 512 + 2048]); \
    gl_lds16(gQ + (k0), &LS[nb][1][w * 512]); \
    gl_lds16(gQ + (k0) + 32 * 512, &LS[nb][1][w * 512 + 2048]);

    STAGE_PQ(0, 0)
    f16x8 cs00 = *(const f16x8*)(Sw0);
    f16x8 cs01 = *(const f16x8*)(Sw0 + 512);
    f16x8 cs10 = *(const f16x8*)(Sw1);
    f16x8 cs11 = *(const f16x8*)(Sw1 + 512);
    f16x8 cc00 = *(const f16x8*)(Cw0);
    f16x8 cc01 = *(const f16x8*)(Cw0 + 512);
    f16x8 cc10 = *(const f16x8*)(Cw1);
    f16x8 cc11 = *(const f16x8*)(Cw1 + 512);
    __syncthreads();

#pragma unroll
    for (int step = 0; step < 8; ++step) {
        int buf = step & 1;
        f16x8 ns00, ns01, ns10, ns11, nc00, nc01, nc10, nc11;
        if (step < 7) {
            STAGE_PQ(buf ^ 1, (step + 1) * 64)
            int kc = (2 * step + 2) * 512;
            ns00 = *(const f16x8*)(Sw0 + kc);
            ns01 = *(const f16x8*)(Sw0 + kc + 512);
            ns10 = *(const f16x8*)(Sw1 + kc);
            ns11 = *(const f16x8*)(Sw1 + kc + 512);
            nc00 = *(const f16x8*)(Cw0 + kc);
            nc01 = *(const f16x8*)(Cw0 + kc + 512);
            nc10 = *(const f16x8*)(Cw1 + kc);
            nc11 = *(const f16x8*)(Cw1 + kc + 512);
        }
        {   // ks = 0
            f16x8 p0 = *(const f16x8*)&LS[buf][0][FOFF(rB0, lc)];
            f16x8 p1 = *(const f16x8*)&LS[buf][0][FOFF(rB1, lc)];
            x00 = MFMA16(cs00, p0, x00);
            x01 = MFMA16(cs00, p1, x01);
            x10 = MFMA16(cs10, p0, x10);
            x11 = MFMA16(cs10, p1, x11);
            f16x8 q0 = *(const f16x8*)&LS[buf][1][FOFF(rB0, lc)];
            f16x8 q1 = *(const f16x8*)&LS[buf][1][FOFF(rB1, lc)];
            y00 = MFMA16(cc00, q0, y00);
            y01 = MFMA16(cc00, q1, y01);
            y10 = MFMA16(cc10, q0, y10);
            y11 = MFMA16(cc10, q1, y11);
        }
        {   // ks = 1
            f16x8 p0 = *(const f16x8*)&LS[buf][0][FOFF(rB0, lc + 4)];
            f16x8 p1 = *(const f16x8*)&LS[buf][0][FOFF(rB1, lc + 4)];
            x00 = MFMA16(cs01, p0, x00);
            x01 = MFMA16(cs01, p1, x01);
            x10 = MFMA16(cs11, p0, x10);
            x11 = MFMA16(cs11, p1, x11);
            f16x8 q0 = *(const f16x8*)&LS[buf][1][FOFF(rB0, lc + 4)];
            f16x8 q1 = *(const f16x8*)&LS[buf][1][FOFF(rB1, lc + 4)];
            y00 = MFMA16(cc01, q0, y00);
            y01 = MFMA16(cc01, q1, y01);
            y10 = MFMA16(cc11, q0, y10);
            y11 = MFMA16(cc11, q1, y11);
        }
        __syncthreads();
        if (step < 7) {
            cs00 = ns00; cs01 = ns01; cs10 = ns10; cs11 = ns11;
            cc00 = nc00; cc01 = nc01; cc10 = nc10; cc11 = nc11;
        }
    }
#undef STAGE_PQ

    int crow = m0 + wr * 32 + lc * 4;   // v
    int ccol = n0 + wc * 32 + lr;       // u
    const f32x4* xs[2][2] = {{&x00, &x01}, {&x10, &x11}};
    const f32x4* ys[2][2] = {{&y00, &y01}, {&y10, &y11}};
#pragma unroll
    for (int q = 0; q < 2; ++q)
#pragma unroll
        for (int pp = 0; pp < 2; ++pp) {
            int u = ccol + pp * 16;
            float eu = (u ? 2.0f : 1.0f) * kInvHW;
#pragma unroll
            for (int rr = 0; rr < 4; ++rr) {
                int v = crow + q * 16 + rr;
                float gx = (*xs[q][pp])[rr];
                float gy = (*ys[q][pp])[rr];
                float num = kPiOver512 * ((float)v * gx + (float)u * gy);
                float den = 1e-10f - kPi2Norm * (float)(u * u + v * v);
                float eps = (v ? 2.0f : 1.0f) * eu;
                hst(eps * num / den, o + v * 512 + u);
            }
        }
}

// ------- d = s-t (nat + T, fp16) + partials; z==6: frag-major tables --------
__global__ __launch_bounds__(256) void diff_split_tab(
    const float* __restrict__ s, const float* __restrict__ t, const float* __restrict__ m,
    short* __restrict__ dn, short* __restrict__ dt,
    short* __restrict__ Mc, short* __restrict__ Ms,
    short* __restrict__ McT, short* __restrict__ GT,
    float* __restrict__ mt, float* __restrict__ mi)
{
    int z = blockIdx.z;
    if (z == 6) {
        int bid = blockIdx.y * 16 + blockIdx.x;
        if (bid >= 128) return;
        int g = bid * 256 + threadIdx.x;          // 0..32767
        int f = g >> 6, lane = g & 63;
        int r  = ((f >> 4) << 4) | (lane & 15);
        int kb = ((f & 15) << 5) | ((lane >> 4) << 3);
        f16x8 vmc, vms, vmct, vgt;
#pragma unroll
        for (int e = 0; e < 8; ++e) {
            int k = kb + e;
            int p1 = (r * (2 * k + 1)) & 2047;
            float s1, c1; sincosf((float)p1 * (kPi / 1024.0f), &s1, &c1);
            int p2 = (k * (2 * r + 1)) & 2047;
            float s2, c2; sincosf((float)p2 * (kPi / 1024.0f), &s2, &c2);
            float gt = (kPi / 1024.0f) * (hfun(r + k + 1) + hfun(r - k));
            vmc[e]  = (_Float16)c1;
            vms[e]  = (_Float16)s1;
            vmct[e] = (_Float16)c2;
            vgt[e]  = (_Float16)gt;
        }
        *(f16x8*)(Mc  + (size_t)g * 8) = vmc;
        *(f16x8*)(Ms  + (size_t)g * 8) = vms;
        *(f16x8*)(McT + (size_t)g * 8) = vmct;
        *(f16x8*)(GT  + (size_t)g * 8) = vgt;
        return;
    }

    __shared__ float tile[32][33];
    __shared__ float red[512];
    const float* sz = s + (size_t)z * CH;
    const float* tz = t + (size_t)z * CH;
    const float* mz = m + (size_t)z * CH;
    short* nh = dn + (size_t)z * CH;
    short* th = dt + (size_t)z * CH;
    int bx = blockIdx.x * 32, by = blockIdx.y * 32;
    int tx = threadIdx.x & 31, ty = threadIdx.x >> 5;
    float accT = 0.f, accI = 0.f;
    for (int r = ty; r < 32; r += 8) {
        int idx = (by + r) * 512 + bx + tx;
        float tv = tz[idx];
        float d = sz[idx] - tv;
        tile[r][tx] = d;
        hst(d, nh + idx);
        accT += tv;
        if (z < 3) accI += 1.0f - mz[idx];
    }
    __syncthreads();
    for (int r = ty; r < 32; r += 8) {
        hst(tile[tx][r], th + (bx + r) * 512 + by + tx);
    }
    int tid = threadIdx.x;
    red[tid] = accT; red[256 + tid] = accI;
    __syncthreads();
    for (int s2 = 128; s2 > 0; s2 >>= 1) {
        if (tid < s2) { red[tid] += red[tid + s2]; red[256 + tid] += red[256 + tid + s2]; }
        __syncthreads();
    }
    if (tid == 0) {
        int tileid = blockIdx.y * 16 + blockIdx.x;
        mt[z * 256 + tileid] = red[0];
        if (z < 3) mi[z * 256 + tileid] = red[256];
    }
}

// ---------------- final: out = t + U + shift[z] -----------------------------
__global__ __launch_bounds__(256) void final_out(
    const float* __restrict__ t, const float* __restrict__ U,
    const float* __restrict__ part, float* __restrict__ out)
{
    __shared__ float mtv[6], wmuv[3];
    int tid = threadIdx.x;
    if (tid < 6) {
        float s2 = 0.f;
        for (int k = 0; k < 256; ++k) s2 += part[tid * 256 + k];
        mtv[tid] = s2 * (1.0f / (float)CH);
    }
    if (tid >= 8 && tid < 11) {
        int c = tid - 8;
        float si = 0.f, su = 0.f;
        for (int k = 0; k < 256; ++k) si += part[1536 + c * 256 + k];
        for (int k = 0; k < 64; ++k) su += part[2304 + c * 64 + k];
        wmuv[c] = su / si;
    }
    __syncthreads();
    int n4 = NTOT / 4;
    for (int i = blockIdx.x * blockDim.x + tid; i < n4; i += gridDim.x * blockDim.x) {
        int z = i >> 16;
        int c = z % 3;
        float sh = -mtv[z] + mtv[c] - wmuv[c];
        float4 tv = ((const float4*)t)[i];
        float4 uv = ((const float4*)U)[i];
        ((float4*)out)[i] = make_float4(tv.x + uv.x + sh, tv.y + uv.y + sh,
                                        tv.z + uv.z + sh, tv.w + uv.w + sh);
    }
}

extern "C" void kernel_launch(void* const* d_in, const int* in_sizes, int n_in,
                              void* d_out, int out_size, void* d_ws, size_t ws_size,
                              hipStream_t stream) {
    const float* t = (const float*)d_in[0];
    const float* s = (const float*)d_in[1];
    const float* m = (const float*)d_in[2];
    float* out = (float*)d_out;
    float* F = (float*)d_ws;
    if (ws_size < (size_t)(21 * CH + 4096) * sizeof(float)) return;

    // frag-major fp16 tables: 4 x CH = F[0 .. 2CH)
    short* T = (short*)F;
    short *Mc = T, *Ms = T + (size_t)CH, *McT = T + 2 * (size_t)CH, *GT = T + 3 * (size_t)CH;
    // four fp16 banks, 6CH each (3CH floats)
    short* A_ = (short*)(F + 2  * (size_t)CH);
    short* B_ = (short*)(F + 5  * (size_t)CH);
    short* C_ = (short*)(F + 8  * (size_t)CH);
    short* D_ = (short*)(F + 11 * (size_t)CH);
    float* F0  = F + 14 * (size_t)CH;    // 6 CH f32 (U)
    float* part = F + 20 * (size_t)CH;   // partials

    // d = s-t -> A (nat), B (transposed); partials; z==6: frag-major tables
    diff_split_tab<<<dim3(16, 16, 7), 256, 0, stream>>>(s, t, m, A_, B_,
                                                        Mc, Ms, McT, GT,
                                                        part, part + 1536);

    // L1: gx = d~GT, gyT = dT~GT + mask(+T) -> uxT (C), uyT (D)
    gemm_l1<<<dim3(8, 8, 12), 256, 0, stream>>>(A_, B_, GT, m, C_, D_);

    // L2: P = Mc~uxT -> A ; Q = Ms~uyT -> B   (table = A-side)
    gemm_tn<1, 1><<<dim3(8, 8, 12), 256, 0, stream>>>(
        Mc, C_, CH, nullptr, A_, CH,
        Ms, D_, CH, nullptr, B_, CH, 6, nullptr, nullptr);

    // L3: GxT = Ms~P & GyT = Mc~Q + napply -> npT (C)
    gemm_l3<<<dim3(8, 8, 6), 256, 0, stream>>>(Ms, Mc, A_, B_, C_);

    // L4: R = McT~npT -> D   (table = A-side)
    gemm_tn<1, 1><<<dim3(8, 8, 6), 256, 0, stream>>>(
        McT, C_, CH, nullptr, D_, CH,
        McT, C_, CH, nullptr, D_, CH, 6, nullptr, nullptr);

    // L5: U = R~McT -> F0 + masked-dot partials  (table = B-side)
    gemm_tn<2, 0><<<dim3(8, 8, 6), 256, 0, stream>>>(
        McT, D_, CH, F0, nullptr, CH,
        McT, D_, CH, F0, nullptr, CH, 6, m, part + 2304);

    // out = t + U + shift
    final_out<<<768, 256, 0, stream>>>(t, F0, part, out);
}

// Round 10
// 65.568 us; speedup vs baseline: 1.1009x; 1.1009x over previous
//
#include <hip/hip_runtime.h>

// Poisson composition via real DCT/DST algebra on matrix cores, single-fp16
// MFMA (f32 accumulate). 7 launches. Round-8 structure (both operands
// LDS-staged, BK=64 dbuf, XCD-chunked swizzle); L1/L2 use 64x128 block tiles
// (wave 32x64: 6 ds_read -> 8 MFMA per ks) to relieve the LDS pipe.
// Chain (TN GEMMs, C[m][n] = sum_k A[m][k]*Bt[n][k], fp16 operands):
//   d=s-t (nat->A, T->B; z==6 builds tables) ;
//   L1: gx=d~GT, gyT=dT~GT + mask(+T) -> uxT(C), uyT(D)   [64x128 tiles]
//   L2: P=Mc~uxT -> A, Q=Ms~uyT -> B                      [64x128 tiles]
//   L3: GxT=Ms~P & GyT=Mc~Q + napply -> npT(C)            [64x64 dual]
//   L4: R=McT~npT -> D ; L5: U=R~McT -> F0 (+ partials)   [64x64]
//   final_out: out = t + U + shift[z].

#define CH 262144   // 512*512
#define NCH 6
#define NTOT (NCH*CH)

typedef _Float16 f16x8 __attribute__((ext_vector_type(8)));
typedef float f32x4  __attribute__((ext_vector_type(4)));

static constexpr float kPi        = 3.14159265358979323846f;
static constexpr float kPiOver512 = 0.006135923151542565f;   // pi/512
static constexpr float kPi2Norm   = 3.7649933338155804e-05f; // pi^2/512^2
static constexpr float kInvHW     = 3.814697265625e-06f;     // 1/512^2

__device__ __forceinline__ void hst(float v, short* p) {
    *reinterpret_cast<_Float16*>(p) = (_Float16)v;
}

__device__ __forceinline__ float hfun(int k) {
    if (k == 0) return 0.f;
    float sgn = 1.f;
    if (k < 0) { k = -k; sgn = -1.f; }
    if (k > 512) { k = 1024 - k; sgn = -sgn; }
    float sv, cv;
    sincosf((float)k * (kPi / 1024.0f), &sv, &cv);
    float v = cv / sv;
    if (k & 1) v = -v;
    return sgn * v;
}

// XCD-chunked swizzle (nwg % 8 == 0)
__device__ __forceinline__ void xcd_remap(int& bx, int& by, int& bz) {
    int nx = gridDim.x, ny = gridDim.y;
    int nwg = nx * ny * gridDim.z;
    int w = blockIdx.x + nx * (blockIdx.y + ny * blockIdx.z);
    int s = (w & 7) * (nwg >> 3) + (w >> 3);
    bx = s % nx; s /= nx;
    by = s % ny;
    bz = s / ny;
}

__device__ __forceinline__ void gl_lds16(const short* g, const short* l) {
    __builtin_amdgcn_global_load_lds(
        (const __attribute__((address_space(1))) void*)g,
        (__attribute__((address_space(3))) void*)l, 16, 0, 0);
}

// LDS tiles: row r slot s holds global kchunk s ^ (r&7)
#define FOFF(r, j) (((r) << 6) + 8 * ((j) ^ ((r) & 7)))
#define MFMA16(a, b, c) __builtin_amdgcn_mfma_f32_16x16x32_f16(a, b, c, 0, 0, 0)

// ================= 64x64-tile dual-op GEMM (L4/L5) =================
// OM: 1 = fp16 out; 2 = fp32 C + masked-dot partials
template<int OM>
__global__ __launch_bounds__(256) void gemm_tn(
    const short* __restrict__ A0, int sA0, const short* __restrict__ B0, int sB0,
    float* __restrict__ Cf0, short* __restrict__ O0, int sC0,
    const short* __restrict__ A1, int sA1, const short* __restrict__ B1, int sB1,
    float* __restrict__ Cf1, short* __restrict__ O1, int sC1,
    int zsplit, const float* __restrict__ msk, float* __restrict__ redp)
{
    __shared__ short LS[2][2][4096];   // [buf][A,B][64x64 fp16]
    int bx, by, z;
    xcd_remap(bx, by, z);
    const short *A, *B; float* Cf; short* O;
    if (z < zsplit) {
        A = A0 + (size_t)z * sA0; B = B0 + (size_t)z * sB0;
        Cf = Cf0 ? Cf0 + (size_t)z * sC0 : nullptr;
        O  = O0 ? O0 + (size_t)z * sC0 : nullptr;
    } else {
        int zz = z - zsplit;
        A = A1 + (size_t)zz * sA1; B = B1 + (size_t)zz * sB1;
        Cf = Cf1 ? Cf1 + (size_t)zz * sC1 : nullptr;
        O  = O1 ? O1 + (size_t)zz * sC1 : nullptr;
    }
    int tid = threadIdx.x;
    int l = tid & 63, w = tid >> 6;
    int m0 = by * 64, n0 = bx * 64;

    int srow = w * 8 + (l >> 3);
    int skc  = (l & 7) ^ ((l >> 3) & 7);
    const short* gA = A + (size_t)(m0 + srow) * 512 + 8 * skc;
    const short* gB = B + (size_t)(n0 + srow) * 512 + 8 * skc;

    int wr = w >> 1, wc = w & 1;
    int lr = l & 15, lc = l >> 4;
    int rA0 = wr * 32 + lr, rA1 = rA0 + 16;
    int rB0 = wc * 32 + lr, rB1 = rB0 + 16;

    f32x4 a00 = {0,0,0,0}, a01 = a00, a10 = a00, a11 = a00;

#define STAGE_AB(nb, k0) \
    gl_lds16(gA + (k0), &LS[nb][0][w * 512]); \
    gl_lds16(gA + (k0) + 32 * 512, &LS[nb][0][w * 512 + 2048]); \
    gl_lds16(gB + (k0), &LS[nb][1][w * 512]); \
    gl_lds16(gB + (k0) + 32 * 512, &LS[nb][1][w * 512 + 2048]);

    STAGE_AB(0, 0)
    __syncthreads();

    for (int step = 0; step < 8; ++step) {
        int buf = step & 1;
        if (step < 7) { STAGE_AB(buf ^ 1, (step + 1) * 64) }
#pragma unroll
        for (int ks = 0; ks < 2; ++ks) {
            int j = lc + 4 * ks;
            f16x8 va0 = *(const f16x8*)&LS[buf][0][FOFF(rA0, j)];
            f16x8 va1 = *(const f16x8*)&LS[buf][0][FOFF(rA1, j)];
            f16x8 vb0 = *(const f16x8*)&LS[buf][1][FOFF(rB0, j)];
            f16x8 vb1 = *(const f16x8*)&LS[buf][1][FOFF(rB1, j)];
            a00 = MFMA16(va0, vb0, a00);
            a01 = MFMA16(va0, vb1, a01);
            a10 = MFMA16(va1, vb0, a10);
            a11 = MFMA16(va1, vb1, a11);
        }
        __syncthreads();
    }
#undef STAGE_AB

    int crow = m0 + wr * 32 + lc * 4;
    int ccol = n0 + wc * 32 + lr;
    const f32x4* accs[2][2] = {{&a00, &a01}, {&a10, &a11}};
    float lsum = 0.f;
#pragma unroll
    for (int q = 0; q < 2; ++q)
#pragma unroll
        for (int pp = 0; pp < 2; ++pp)
#pragma unroll
            for (int rr = 0; rr < 4; ++rr) {
                int idx = (crow + q * 16 + rr) * 512 + ccol + pp * 16;
                float v = (*accs[q][pp])[rr];
                if (OM == 1) {
                    hst(v, O + idx);
                } else {
                    Cf[idx] = v;
                    lsum += v * (1.0f - msk[(size_t)z * CH + idx]);
                }
            }
    if (OM == 2) {
        float* red = (float*)LS;
        red[tid] = lsum;
        __syncthreads();
        for (int s2 = 128; s2 > 0; s2 >>= 1) {
            if (tid < s2) red[tid] += red[tid + s2];
            __syncthreads();
        }
        if (tid == 0) redp[z * 64 + by * 8 + bx] = red[0];
    }
}

// ================= 64x128-tile wide GEMM (L2) =================
// A-side (64 rows) staged at LS[buf][0..4096); B-side (128 rows) at [4096..12288)
__global__ __launch_bounds__(256) void gemm_w(
    const short* __restrict__ T0, const short* __restrict__ X0,
    short* __restrict__ O0,
    const short* __restrict__ T1, const short* __restrict__ X1,
    short* __restrict__ O1, int zsplit)
{
    __shared__ short LS[2][12288];   // 48 KB
    int bx, by, z;
    xcd_remap(bx, by, z);
    const short *A, *B; short* O;
    if (z < zsplit) { A = T0; B = X0 + (size_t)z * CH; O = O0 + (size_t)z * CH; }
    else { int zz = z - zsplit; A = T1; B = X1 + (size_t)zz * CH; O = O1 + (size_t)zz * CH; }

    int tid = threadIdx.x;
    int l = tid & 63, w = tid >> 6;
    int m0 = by * 64, n0 = bx * 128;

    int srow = w * 8 + (l >> 3);
    int skc  = (l & 7) ^ ((l >> 3) & 7);
    const short* gA = A + (size_t)(m0 + srow) * 512 + 8 * skc;
    const short* gB = B + (size_t)(n0 + srow) * 512 + 8 * skc;

    int wr = w >> 1, wc = w & 1;
    int lr = l & 15, lc = l >> 4;
    int rA0 = wr * 32 + lr, rA1 = rA0 + 16;
    int rB = wc * 64 + lr;

    f32x4 acc[2][4];
#pragma unroll
    for (int q = 0; q < 2; ++q)
#pragma unroll
        for (int pb = 0; pb < 4; ++pb) acc[q][pb] = (f32x4){0.f,0.f,0.f,0.f};

#define STAGE_W(nb, k0) \
    gl_lds16(gA + (k0),            &LS[nb][w * 512]); \
    gl_lds16(gA + (k0) + 32 * 512, &LS[nb][w * 512 + 2048]); \
    gl_lds16(gB + (k0),            &LS[nb][4096 + w * 512]); \
    gl_lds16(gB + (k0) + 32 * 512, &LS[nb][4096 + w * 512 + 2048]); \
    gl_lds16(gB + (k0) + 64 * 512, &LS[nb][4096 + w * 512 + 4096]); \
    gl_lds16(gB + (k0) + 96 * 512, &LS[nb][4096 + w * 512 + 6144]);

    STAGE_W(0, 0)
    __syncthreads();

    for (int step = 0; step < 8; ++step) {
        int buf = step & 1;
        if (step < 7) { STAGE_W(buf ^ 1, (step + 1) * 64) }
#pragma unroll
        for (int ks = 0; ks < 2; ++ks) {
            int j = lc + 4 * ks;
            f16x8 va0 = *(const f16x8*)&LS[buf][FOFF(rA0, j)];
            f16x8 va1 = *(const f16x8*)&LS[buf][FOFF(rA1, j)];
#pragma unroll
            for (int pb = 0; pb < 4; ++pb) {
                f16x8 vb = *(const f16x8*)&LS[buf][4096 + FOFF(rB + 16 * pb, j)];
                acc[0][pb] = MFMA16(va0, vb, acc[0][pb]);
                acc[1][pb] = MFMA16(va1, vb, acc[1][pb]);
            }
        }
        __syncthreads();
    }
#undef STAGE_W

    int crow = m0 + wr * 32 + lc * 4;
    int ccol = n0 + wc * 64 + lr;
#pragma unroll
    for (int q = 0; q < 2; ++q)
#pragma unroll
        for (int pb = 0; pb < 4; ++pb)
#pragma unroll
            for (int rr = 0; rr < 4; ++rr)
                hst(acc[q][pb][rr], O + (crow + q * 16 + rr) * 512 + ccol + pb * 16);
}

// ================= 64x128-tile L1 (mask + transpose epilogues) =================
__global__ __launch_bounds__(256) void gemm_l1w(
    const short* __restrict__ dn, const short* __restrict__ dt,
    const short* __restrict__ GT, const float* __restrict__ msk,
    short* __restrict__ C_, short* __restrict__ D_)
{
    __shared__ short LS[2][12288];   // 48 KB; epilogue tile 128x65 f32 = 33.3 KB
    int bx, by, z;
    xcd_remap(bx, by, z);
    bool gxp = z < 6;
    int zz = gxp ? z : z - 6;
    const short* A = (gxp ? dn : dt) + (size_t)zz * CH;
    const float* mz = msk + (size_t)zz * CH;

    int tid = threadIdx.x;
    int l = tid & 63, w = tid >> 6;
    int m0 = by * 64, n0 = bx * 128;

    int srow = w * 8 + (l >> 3);
    int skc  = (l & 7) ^ ((l >> 3) & 7);
    const short* gA = A + (size_t)(m0 + srow) * 512 + 8 * skc;
    const short* gB = GT + (size_t)(n0 + srow) * 512 + 8 * skc;

    int wr = w >> 1, wc = w & 1;
    int lr = l & 15, lc = l >> 4;
    int rA0 = wr * 32 + lr, rA1 = rA0 + 16;
    int rB = wc * 64 + lr;

    f32x4 acc[2][4];
#pragma unroll
    for (int q = 0; q < 2; ++q)
#pragma unroll
        for (int pb = 0; pb < 4; ++pb) acc[q][pb] = (f32x4){0.f,0.f,0.f,0.f};

#define STAGE_W(nb, k0) \
    gl_lds16(gA + (k0),            &LS[nb][w * 512]); \
    gl_lds16(gA + (k0) + 32 * 512, &LS[nb][w * 512 + 2048]); \
    gl_lds16(gB + (k0),            &LS[nb][4096 + w * 512]); \
    gl_lds16(gB + (k0) + 32 * 512, &LS[nb][4096 + w * 512 + 2048]); \
    gl_lds16(gB + (k0) + 64 * 512, &LS[nb][4096 + w * 512 + 4096]); \
    gl_lds16(gB + (k0) + 96 * 512, &LS[nb][4096 + w * 512 + 6144]);

    STAGE_W(0, 0)
    __syncthreads();

    for (int step = 0; step < 8; ++step) {
        int buf = step & 1;
        if (step < 7) { STAGE_W(buf ^ 1, (step + 1) * 64) }
#pragma unroll
        for (int ks = 0; ks < 2; ++ks) {
            int j = lc + 4 * ks;
            f16x8 va0 = *(const f16x8*)&LS[buf][FOFF(rA0, j)];
            f16x8 va1 = *(const f16x8*)&LS[buf][FOFF(rA1, j)];
#pragma unroll
            for (int pb = 0; pb < 4; ++pb) {
                f16x8 vb = *(const f16x8*)&LS[buf][4096 + FOFF(rB + 16 * pb, j)];
                acc[0][pb] = MFMA16(va0, vb, acc[0][pb]);
                acc[1][pb] = MFMA16(va1, vb, acc[1][pb]);
            }
        }
        __syncthreads();
    }
#undef STAGE_W

    float* tile = (float*)LS;   // [128][65] f32

    if (gxp) {
        // ux = m .* gx; LDS transpose; write uxT fp16 at [j][i]
        short* o = C_ + (size_t)zz * CH;
#pragma unroll
        for (int q = 0; q < 2; ++q)
#pragma unroll
            for (int pb = 0; pb < 4; ++pb)
#pragma unroll
                for (int rr = 0; rr < 4; ++rr) {
                    int r = wr * 32 + lc * 4 + q * 16 + rr;     // 0..63
                    int c = wc * 64 + pb * 16 + lr;             // 0..127
                    float v = acc[q][pb][rr] * mz[(size_t)(m0 + r) * 512 + n0 + c];
                    tile[c * 65 + r] = v;
                }
        __syncthreads();
#pragma unroll
        for (int pass = 0; pass < 32; ++pass) {
            int jj = pass * 4 + (tid >> 6);   // 0..127
            int ii = tid & 63;                // 0..63
            hst(tile[jj * 65 + ii], o + (n0 + jj) * 512 + m0 + ii);
        }
    } else {
        // uyT = gyT .* m^T : load m^T tile, multiply, natural write
        short* o = D_ + (size_t)zz * CH;
#pragma unroll
        for (int pass = 0; pass < 32; ++pass) {
            int cc = pass * 4 + (tid >> 6);   // 0..127
            int rr2 = tid & 63;               // 0..63
            tile[cc * 65 + rr2] = mz[(size_t)(n0 + cc) * 512 + m0 + rr2];
        }
        __syncthreads();
#pragma unroll
        for (int q = 0; q < 2; ++q)
#pragma unroll
            for (int pb = 0; pb < 4; ++pb)
#pragma unroll
                for (int rr = 0; rr < 4; ++rr) {
                    int r = wr * 32 + lc * 4 + q * 16 + rr;
                    int c = wc * 64 + pb * 16 + lr;
                    float v = acc[q][pb][rr] * tile[c * 65 + r];
                    hst(v, o + (m0 + r) * 512 + n0 + c);
                }
    }
}

// ================= L3 fused (round-8, 64x64 dual) =================
__global__ __launch_bounds__(256) void gemm_l3(
    const short* __restrict__ Ms, const short* __restrict__ Mc,
    const short* __restrict__ P, const short* __restrict__ Q,
    short* __restrict__ O_)
{
    __shared__ short LS[2][4][4096];   // Ms, Mc, P, Q
    int bx, by, z;
    xcd_remap(bx, by, z);
    const short* pz = P + (size_t)z * CH;
    const short* qz = Q + (size_t)z * CH;
    short* o = O_ + (size_t)z * CH;

    int tid = threadIdx.x;
    int l = tid & 63, w = tid >> 6;
    int m0 = by * 64, n0 = bx * 64;

    int srow = w * 8 + (l >> 3);
    int skc  = (l & 7) ^ ((l >> 3) & 7);
    size_t ga = (size_t)(m0 + srow) * 512 + 8 * skc;
    size_t gb = (size_t)(n0 + srow) * 512 + 8 * skc;
    const short* g0 = Ms + ga;
    const short* g1 = Mc + ga;
    const short* g2 = pz + gb;
    const short* g3 = qz + gb;

    int wr = w >> 1, wc = w & 1;
    int lr = l & 15, lc = l >> 4;
    int rA0 = wr * 32 + lr, rA1 = rA0 + 16;
    int rB0 = wc * 32 + lr, rB1 = rB0 + 16;

    f32x4 x00 = {0,0,0,0}, x01 = x00, x10 = x00, x11 = x00;
    f32x4 y00 = x00, y01 = x00, y10 = x00, y11 = x00;

#define STAGE_L3(nb, k0) \
    gl_lds16(g0 + (k0), &LS[nb][0][w * 512]); \
    gl_lds16(g0 + (k0) + 32 * 512, &LS[nb][0][w * 512 + 2048]); \
    gl_lds16(g1 + (k0), &LS[nb][1][w * 512]); \
    gl_lds16(g1 + (k0) + 32 * 512, &LS[nb][1][w * 512 + 2048]); \
    gl_lds16(g2 + (k0), &LS[nb][2][w * 512]); \
    gl_lds16(g2 + (k0) + 32 * 512, &LS[nb][2][w * 512 + 2048]); \
    gl_lds16(g3 + (k0), &LS[nb][3][w * 512]); \
    gl_lds16(g3 + (k0) + 32 * 512, &LS[nb][3][w * 512 + 2048]);

    STAGE_L3(0, 0)
    __syncthreads();

    for (int step = 0; step < 8; ++step) {
        int buf = step & 1;
        if (step < 7) { STAGE_L3(buf ^ 1, (step + 1) * 64) }
#pragma unroll
        for (int ks = 0; ks < 2; ++ks) {
            int j = lc + 4 * ks;
            f16x8 s0 = *(const f16x8*)&LS[buf][0][FOFF(rA0, j)];
            f16x8 s1 = *(const f16x8*)&LS[buf][0][FOFF(rA1, j)];
            f16x8 p0 = *(const f16x8*)&LS[buf][2][FOFF(rB0, j)];
            f16x8 p1 = *(const f16x8*)&LS[buf][2][FOFF(rB1, j)];
            x00 = MFMA16(s0, p0, x00);
            x01 = MFMA16(s0, p1, x01);
            x10 = MFMA16(s1, p0, x10);
            x11 = MFMA16(s1, p1, x11);
            f16x8 c0 = *(const f16x8*)&LS[buf][1][FOFF(rA0, j)];
            f16x8 c1 = *(const f16x8*)&LS[buf][1][FOFF(rA1, j)];
            f16x8 q0 = *(const f16x8*)&LS[buf][3][FOFF(rB0, j)];
            f16x8 q1 = *(const f16x8*)&LS[buf][3][FOFF(rB1, j)];
            y00 = MFMA16(c0, q0, y00);
            y01 = MFMA16(c0, q1, y01);
            y10 = MFMA16(c1, q0, y10);
            y11 = MFMA16(c1, q1, y11);
        }
        __syncthreads();
    }
#undef STAGE_L3

    int crow = m0 + wr * 32 + lc * 4;   // v
    int ccol = n0 + wc * 32 + lr;       // u
    const f32x4* xs[2][2] = {{&x00, &x01}, {&x10, &x11}};
    const f32x4* ys[2][2] = {{&y00, &y01}, {&y10, &y11}};
#pragma unroll
    for (int q = 0; q < 2; ++q)
#pragma unroll
        for (int pp = 0; pp < 2; ++pp) {
            int u = ccol + pp * 16;
            float eu = (u ? 2.0f : 1.0f) * kInvHW;
#pragma unroll
            for (int rr = 0; rr < 4; ++rr) {
                int v = crow + q * 16 + rr;
                float gx = (*xs[q][pp])[rr];
                float gy = (*ys[q][pp])[rr];
                float num = kPiOver512 * ((float)v * gx + (float)u * gy);
                float den = 1e-10f - kPi2Norm * (float)(u * u + v * v);
                float eps = (v ? 2.0f : 1.0f) * eu;
                hst(eps * num / den, o + v * 512 + u);
            }
        }
}

// ------- d = s-t (nat + T, fp16) + partials; z==6 builds row-major tables ---
__global__ __launch_bounds__(256) void diff_split_tab(
    const float* __restrict__ s, const float* __restrict__ t, const float* __restrict__ m,
    short* __restrict__ dn, short* __restrict__ dt,
    short* __restrict__ Mc, short* __restrict__ Ms,
    short* __restrict__ McT, short* __restrict__ GT,
    float* __restrict__ mt, float* __restrict__ mi)
{
    int z = blockIdx.z;
    if (z == 6) {
        int bid = blockIdx.y * 16 + blockIdx.x;   // 0..255
        int base = (bid * 256 + threadIdx.x) * 4;
#pragma unroll
        for (int e = 0; e < 4; ++e) {
            int idx = base + e;
            int a = idx >> 9, b = idx & 511;
            int p1 = (a * (2 * b + 1)) & 2047;
            float s1, c1; sincosf((float)p1 * (kPi / 1024.0f), &s1, &c1);
            hst(c1, Mc + idx);
            hst(s1, Ms + idx);
            int p2 = (b * (2 * a + 1)) & 2047;
            float s2, c2; sincosf((float)p2 * (kPi / 1024.0f), &s2, &c2);
            hst(c2, McT + idx);
            float g = (kPi / 1024.0f) * (hfun(a + b + 1) + hfun(a - b));
            hst(g, GT + idx);
        }
        return;
    }

    __shared__ float tile[32][33];
    __shared__ float red[512];
    const float* sz = s + (size_t)z * CH;
    const float* tz = t + (size_t)z * CH;
    const float* mz = m + (size_t)z * CH;
    short* nh = dn + (size_t)z * CH;
    short* th = dt + (size_t)z * CH;
    int bx = blockIdx.x * 32, by = blockIdx.y * 32;
    int tx = threadIdx.x & 31, ty = threadIdx.x >> 5;
    float accT = 0.f, accI = 0.f;
    for (int r = ty; r < 32; r += 8) {
        int idx = (by + r) * 512 + bx + tx;
        float tv = tz[idx];
        float d = sz[idx] - tv;
        tile[r][tx] = d;
        hst(d, nh + idx);
        accT += tv;
        if (z < 3) accI += 1.0f - mz[idx];
    }
    __syncthreads();
    for (int r = ty; r < 32; r += 8) {
        hst(tile[tx][r], th + (bx + r) * 512 + by + tx);
    }
    int tid = threadIdx.x;
    red[tid] = accT; red[256 + tid] = accI;
    __syncthreads();
    for (int s2 = 128; s2 > 0; s2 >>= 1) {
        if (tid < s2) { red[tid] += red[tid + s2]; red[256 + tid] += red[256 + tid + s2]; }
        __syncthreads();
    }
    if (tid == 0) {
        int tileid = blockIdx.y * 16 + blockIdx.x;
        mt[z * 256 + tileid] = red[0];
        if (z < 3) mi[z * 256 + tileid] = red[256];
    }
}

// ---------------- final: out = t + U + shift[z] -----------------------------
__global__ __launch_bounds__(256) void final_out(
    const float* __restrict__ t, const float* __restrict__ U,
    const float* __restrict__ part, float* __restrict__ out)
{
    __shared__ float mtv[6], wmuv[3];
    int tid = threadIdx.x;
    if (tid < 6) {
        float s2 = 0.f;
        for (int k = 0; k < 256; ++k) s2 += part[tid * 256 + k];
        mtv[tid] = s2 * (1.0f / (float)CH);
    }
    if (tid >= 8 && tid < 11) {
        int c = tid - 8;
        float si = 0.f, su = 0.f;
        for (int k = 0; k < 256; ++k) si += part[1536 + c * 256 + k];
        for (int k = 0; k < 64; ++k) su += part[2304 + c * 64 + k];
        wmuv[c] = su / si;
    }
    __syncthreads();
    int n4 = NTOT / 4;
    for (int i = blockIdx.x * blockDim.x + tid; i < n4; i += gridDim.x * blockDim.x) {
        int z = i >> 16;
        int c = z % 3;
        float sh = -mtv[z] + mtv[c] - wmuv[c];
        float4 tv = ((const float4*)t)[i];
        float4 uv = ((const float4*)U)[i];
        ((float4*)out)[i] = make_float4(tv.x + uv.x + sh, tv.y + uv.y + sh,
                                        tv.z + uv.z + sh, tv.w + uv.w + sh);
    }
}

extern "C" void kernel_launch(void* const* d_in, const int* in_sizes, int n_in,
                              void* d_out, int out_size, void* d_ws, size_t ws_size,
                              hipStream_t stream) {
    const float* t = (const float*)d_in[0];
    const float* s = (const float*)d_in[1];
    const float* m = (const float*)d_in[2];
    float* out = (float*)d_out;
    float* F = (float*)d_ws;
    if (ws_size < (size_t)(21 * CH + 4096) * sizeof(float)) return;

    // row-major fp16 tables: 4 x CH = F[0 .. 2CH)
    short* T = (short*)F;
    short *Mc = T, *Ms = T + (size_t)CH, *McT = T + 2 * (size_t)CH, *GT = T + 3 * (size_t)CH;
    // four fp16 banks, 6CH each (3CH floats)
    short* A_ = (short*)(F + 2  * (size_t)CH);
    short* B_ = (short*)(F + 5  * (size_t)CH);
    short* C_ = (short*)(F + 8  * (size_t)CH);
    short* D_ = (short*)(F + 11 * (size_t)CH);
    float* F0  = F + 14 * (size_t)CH;    // 6 CH f32 (U)
    float* part = F + 20 * (size_t)CH;   // partials

    // d = s-t -> A (nat), B (transposed); partials; z==6: tables
    diff_split_tab<<<dim3(16, 16, 7), 256, 0, stream>>>(s, t, m, A_, B_,
                                                        Mc, Ms, McT, GT,
                                                        part, part + 1536);

    // L1 (64x128): gx = d~GT, gyT = dT~GT + mask(+T) -> uxT (C), uyT (D)
    gemm_l1w<<<dim3(4, 8, 12), 256, 0, stream>>>(A_, B_, GT, m, C_, D_);

    // L2 (64x128): P = Mc~uxT -> A ; Q = Ms~uyT -> B
    gemm_w<<<dim3(4, 8, 12), 256, 0, stream>>>(Mc, C_, A_, Ms, D_, B_, 6);

    // L3: GxT = Ms~P & GyT = Mc~Q + napply -> npT (C)
    gemm_l3<<<dim3(8, 8, 6), 256, 0, stream>>>(Ms, Mc, A_, B_, C_);

    // L4: R = McT~npT -> D
    gemm_tn<1><<<dim3(8, 8, 6), 256, 0, stream>>>(
        McT, 0, C_, CH, nullptr, D_, CH,
        McT, 0, C_, CH, nullptr, D_, CH, 6, nullptr, nullptr);

    // L5: U = R~McT -> F0 + masked-dot partials
    gemm_tn<2><<<dim3(8, 8, 6), 256, 0, stream>>>(
        D_, CH, McT, 0, F0, nullptr, CH,
        D_, CH, McT, 0, F0, nullptr, CH, 6, m, part + 2304);

    // out = t + U + shift
    final_out<<<768, 256, 0, stream>>>(t, F0, part, out);
}

// Round 12
// 64.700 us; speedup vs baseline: 1.1157x; 1.0134x over previous
//
#include <hip/hip_runtime.h>

// Poisson composition via real DCT/DST algebra on matrix cores, single-fp16
// MFMA (f32 accumulate). 7 launches. Round-8 structure (both operands
// LDS-staged, BK=64 dbuf, XCD-chunked swizzle) — verified best (64.1 us).
//   logical = (wgid%8)*(nwg/8) + wgid/8  -> each XCD owns contiguous slices;
//   panel re-reads become XCD-local L2 hits.
// Chain (TN GEMMs, C[m][n] = sum_k A[m][k]*Bt[n][k], fp16 operands):
//   d=s-t (nat->A, T->B; z==6 builds tables) ;
//   L1: gx=d~GT, gyT=dT~GT + mask(+T) -> uxT(C), uyT(D)
//   L2: P=Mc~uxT -> A, Q=Ms~uyT -> B
//   L3: GxT=Ms~P & GyT=Mc~Q + napply -> npT(C)
//   L4: R=McT~npT -> D ; L5: U=R~McT -> F0 (+ masked-dot partials)
//   final_out: out = t + U + shift[z].

#define CH 262144   // 512*512
#define NCH 6
#define NTOT (NCH*CH)

typedef _Float16 f16x8 __attribute__((ext_vector_type(8)));
typedef float f32x4  __attribute__((ext_vector_type(4)));

static constexpr float kPi        = 3.14159265358979323846f;
static constexpr float kPiOver512 = 0.006135923151542565f;   // pi/512
static constexpr float kPi2Norm   = 3.7649933338155804e-05f; // pi^2/512^2
static constexpr float kInvHW     = 3.814697265625e-06f;     // 1/512^2

__device__ __forceinline__ void hst(float v, short* p) {
    *reinterpret_cast<_Float16*>(p) = (_Float16)v;
}

__device__ __forceinline__ float hfun(int k) {
    if (k == 0) return 0.f;
    float sgn = 1.f;
    if (k < 0) { k = -k; sgn = -1.f; }
    if (k > 512) { k = 1024 - k; sgn = -sgn; }
    float sv, cv;
    sincosf((float)k * (kPi / 1024.0f), &sv, &cv);
    float v = cv / sv;
    if (k & 1) v = -v;
    return sgn * v;
}

// XCD-chunked swizzle: original wgid w lands on XCD w%8; give XCD k the
// contiguous logical chunk [k*nwg/8, (k+1)*nwg/8). Requires nwg % 8 == 0.
__device__ __forceinline__ void xcd_remap(int& bx, int& by, int& bz) {
    int nx = gridDim.x, ny = gridDim.y;
    int nwg = nx * ny * gridDim.z;
    int w = blockIdx.x + nx * (blockIdx.y + ny * blockIdx.z);
    int s = (w & 7) * (nwg >> 3) + (w >> 3);
    bx = s % nx; s /= nx;
    by = s % ny;
    bz = s / ny;
}

// ---------------- GEMM machinery (BK=64, dbuf LDS both operands) ------------
__device__ __forceinline__ void gl_lds16(const short* g, const short* l) {
    __builtin_amdgcn_global_load_lds(
        (const __attribute__((address_space(1))) void*)g,
        (__attribute__((address_space(3))) void*)l, 16, 0, 0);
}

// LDS tile: 64 rows x 64 k fp16 = 8 KB. Row r, slot s holds global chunk
// s ^ (r&7). Frag read offset for (row r, logical kchunk j):
#define FOFF(r, j) (((r) << 6) + 8 * ((j) ^ ((r) & 7)))
#define MFMA16(a, b, c) __builtin_amdgcn_mfma_f32_16x16x32_f16(a, b, c, 0, 0, 0)

// OM: 1 = fp16 out; 2 = fp32 C + masked-dot partials
template<int OM>
__global__ __launch_bounds__(256) void gemm_tn(
    const short* __restrict__ A0, int sA0, const short* __restrict__ B0, int sB0,
    float* __restrict__ Cf0, short* __restrict__ O0, int sC0,
    const short* __restrict__ A1, int sA1, const short* __restrict__ B1, int sB1,
    float* __restrict__ Cf1, short* __restrict__ O1, int sC1,
    int zsplit, const float* __restrict__ msk, float* __restrict__ redp)
{
    __shared__ short LS[2][2][4096];   // [buf][A,B][64x64 fp16]
    int bx, by, z;
    xcd_remap(bx, by, z);
    const short *A, *B; float* Cf; short* O;
    if (z < zsplit) {
        A = A0 + (size_t)z * sA0; B = B0 + (size_t)z * sB0;
        Cf = Cf0 ? Cf0 + (size_t)z * sC0 : nullptr;
        O  = O0 ? O0 + (size_t)z * sC0 : nullptr;
    } else {
        int zz = z - zsplit;
        A = A1 + (size_t)zz * sA1; B = B1 + (size_t)zz * sB1;
        Cf = Cf1 ? Cf1 + (size_t)zz * sC1 : nullptr;
        O  = O1 ? O1 + (size_t)zz * sC1 : nullptr;
    }
    int tid = threadIdx.x;
    int l = tid & 63, w = tid >> 6;
    int m0 = by * 64, n0 = bx * 64;

    int srow = w * 8 + (l >> 3);
    int skc  = (l & 7) ^ ((l >> 3) & 7);
    const short* gA = A + (size_t)(m0 + srow) * 512 + 8 * skc;
    const short* gB = B + (size_t)(n0 + srow) * 512 + 8 * skc;

    int wr = w >> 1, wc = w & 1;
    int lr = l & 15, lc = l >> 4;
    int rA0 = wr * 32 + lr, rA1 = rA0 + 16;
    int rB0 = wc * 32 + lr, rB1 = rB0 + 16;

    f32x4 a00 = {0,0,0,0}, a01 = a00, a10 = a00, a11 = a00;

#define STAGE_AB(nb, k0) \
    gl_lds16(gA + (k0), &LS[nb][0][w * 512]); \
    gl_lds16(gA + (k0) + 32 * 512, &LS[nb][0][w * 512 + 2048]); \
    gl_lds16(gB + (k0), &LS[nb][1][w * 512]); \
    gl_lds16(gB + (k0) + 32 * 512, &LS[nb][1][w * 512 + 2048]);

    STAGE_AB(0, 0)
    __syncthreads();

    for (int step = 0; step < 8; ++step) {
        int buf = step & 1;
        if (step < 7) { STAGE_AB(buf ^ 1, (step + 1) * 64) }
#pragma unroll
        for (int ks = 0; ks < 2; ++ks) {
            int j = lc + 4 * ks;
            f16x8 va0 = *(const f16x8*)&LS[buf][0][FOFF(rA0, j)];
            f16x8 va1 = *(const f16x8*)&LS[buf][0][FOFF(rA1, j)];
            f16x8 vb0 = *(const f16x8*)&LS[buf][1][FOFF(rB0, j)];
            f16x8 vb1 = *(const f16x8*)&LS[buf][1][FOFF(rB1, j)];
            a00 = MFMA16(va0, vb0, a00);
            a01 = MFMA16(va0, vb1, a01);
            a10 = MFMA16(va1, vb0, a10);
            a11 = MFMA16(va1, vb1, a11);
        }
        __syncthreads();
    }
#undef STAGE_AB

    int crow = m0 + wr * 32 + lc * 4;
    int ccol = n0 + wc * 32 + lr;
    const f32x4* accs[2][2] = {{&a00, &a01}, {&a10, &a11}};
    float lsum = 0.f;
#pragma unroll
    for (int q = 0; q < 2; ++q)
#pragma unroll
        for (int pp = 0; pp < 2; ++pp)
#pragma unroll
            for (int rr = 0; rr < 4; ++rr) {
                int idx = (crow + q * 16 + rr) * 512 + ccol + pp * 16;
                float v = (*accs[q][pp])[rr];
                if (OM == 1) {
                    hst(v, O + idx);
                } else {
                    Cf[idx] = v;
                    lsum += v * (1.0f - msk[(size_t)z * CH + idx]);
                }
            }
    if (OM == 2) {
        float* red = (float*)LS;
        red[tid] = lsum;
        __syncthreads();
        for (int s2 = 128; s2 > 0; s2 >>= 1) {
            if (tid < s2) red[tid] += red[tid + s2];
            __syncthreads();
        }
        if (tid == 0) redp[z * 64 + by * 8 + bx] = red[0];
    }
}

// ---------------- L1 fused: gradients + mask + transpose ----------------
__global__ __launch_bounds__(256) void gemm_l1(
    const short* __restrict__ dn, const short* __restrict__ dt,
    const short* __restrict__ GT, const float* __restrict__ msk,
    short* __restrict__ C_, short* __restrict__ D_)
{
    __shared__ short LS[2][2][4096];
    int bx, by, z;
    xcd_remap(bx, by, z);
    bool gxp = z < 6;
    int zz = gxp ? z : z - 6;
    const short* A = (gxp ? dn : dt) + (size_t)zz * CH;
    const float* mz = msk + (size_t)zz * CH;

    int tid = threadIdx.x;
    int l = tid & 63, w = tid >> 6;
    int m0 = by * 64, n0 = bx * 64;

    int srow = w * 8 + (l >> 3);
    int skc  = (l & 7) ^ ((l >> 3) & 7);
    const short* gA = A + (size_t)(m0 + srow) * 512 + 8 * skc;
    const short* gB = GT + (size_t)(n0 + srow) * 512 + 8 * skc;

    int wr = w >> 1, wc = w & 1;
    int lr = l & 15, lc = l >> 4;
    int rA0 = wr * 32 + lr, rA1 = rA0 + 16;
    int rB0 = wc * 32 + lr, rB1 = rB0 + 16;

    f32x4 a00 = {0,0,0,0}, a01 = a00, a10 = a00, a11 = a00;

#define STAGE_AB(nb, k0) \
    gl_lds16(gA + (k0), &LS[nb][0][w * 512]); \
    gl_lds16(gA + (k0) + 32 * 512, &LS[nb][0][w * 512 + 2048]); \
    gl_lds16(gB + (k0), &LS[nb][1][w * 512]); \
    gl_lds16(gB + (k0) + 32 * 512, &LS[nb][1][w * 512 + 2048]);

    STAGE_AB(0, 0)
    __syncthreads();

    for (int step = 0; step < 8; ++step) {
        int buf = step & 1;
        if (step < 7) { STAGE_AB(buf ^ 1, (step + 1) * 64) }
#pragma unroll
        for (int ks = 0; ks < 2; ++ks) {
            int j = lc + 4 * ks;
            f16x8 va0 = *(const f16x8*)&LS[buf][0][FOFF(rA0, j)];
            f16x8 va1 = *(const f16x8*)&LS[buf][0][FOFF(rA1, j)];
            f16x8 vb0 = *(const f16x8*)&LS[buf][1][FOFF(rB0, j)];
            f16x8 vb1 = *(const f16x8*)&LS[buf][1][FOFF(rB1, j)];
            a00 = MFMA16(va0, vb0, a00);
            a01 = MFMA16(va0, vb1, a01);
            a10 = MFMA16(va1, vb0, a10);
            a11 = MFMA16(va1, vb1, a11);
        }
        __syncthreads();
    }
#undef STAGE_AB

    const f32x4* accs[2][2] = {{&a00, &a01}, {&a10, &a11}};
    float* tile = (float*)LS;   // 64x65 floats = 16640 B

    if (gxp) {
        short* o = C_ + (size_t)zz * CH;
#pragma unroll
        for (int q = 0; q < 2; ++q)
#pragma unroll
            for (int pp = 0; pp < 2; ++pp)
#pragma unroll
                for (int rr = 0; rr < 4; ++rr) {
                    int r = wr * 32 + lc * 4 + q * 16 + rr;
                    int c = wc * 32 + pp * 16 + lr;
                    float v = (*accs[q][pp])[rr] * mz[(size_t)(m0 + r) * 512 + n0 + c];
                    tile[c * 65 + r] = v;
                }
        __syncthreads();
#pragma unroll
        for (int pass = 0; pass < 16; ++pass) {
            int jj = pass * 4 + (tid >> 6);
            int ii = tid & 63;
            hst(tile[jj * 65 + ii], o + (n0 + jj) * 512 + m0 + ii);
        }
    } else {
        short* o = D_ + (size_t)zz * CH;
#pragma unroll
        for (int pass = 0; pass < 16; ++pass) {
            int ii = pass * 4 + (tid >> 6);
            int jj = tid & 63;
            tile[jj * 65 + ii] = mz[(size_t)(n0 + ii) * 512 + m0 + jj];
        }
        __syncthreads();
#pragma unroll
        for (int q = 0; q < 2; ++q)
#pragma unroll
            for (int pp = 0; pp < 2; ++pp)
#pragma unroll
                for (int rr = 0; rr < 4; ++rr) {
                    int r = wr * 32 + lc * 4 + q * 16 + rr;
                    int c = wc * 32 + pp * 16 + lr;
                    float v = (*accs[q][pp])[rr] * tile[r * 65 + c];
                    hst(v, o + (m0 + r) * 512 + n0 + c);
                }
    }
}

// ---------------- L3 fused: GxT & GyT + napply epilogue ----------------
__global__ __launch_bounds__(256) void gemm_l3(
    const short* __restrict__ Ms, const short* __restrict__ Mc,
    const short* __restrict__ P, const short* __restrict__ Q,
    short* __restrict__ O_)
{
    __shared__ short LS[2][4][4096];   // Ms, Mc, P, Q
    int bx, by, z;
    xcd_remap(bx, by, z);
    const short* pz = P + (size_t)z * CH;
    const short* qz = Q + (size_t)z * CH;
    short* o = O_ + (size_t)z * CH;

    int tid = threadIdx.x;
    int l = tid & 63, w = tid >> 6;
    int m0 = by * 64, n0 = bx * 64;

    int srow = w * 8 + (l >> 3);
    int skc  = (l & 7) ^ ((l >> 3) & 7);
    size_t ga = (size_t)(m0 + srow) * 512 + 8 * skc;
    size_t gb = (size_t)(n0 + srow) * 512 + 8 * skc;
    const short* g0 = Ms + ga;
    const short* g1 = Mc + ga;
    const short* g2 = pz + gb;
    const short* g3 = qz + gb;

    int wr = w >> 1, wc = w & 1;
    int lr = l & 15, lc = l >> 4;
    int rA0 = wr * 32 + lr, rA1 = rA0 + 16;
    int rB0 = wc * 32 + lr, rB1 = rB0 + 16;

    f32x4 x00 = {0,0,0,0}, x01 = x00, x10 = x00, x11 = x00;
    f32x4 y00 = x00, y01 = x00, y10 = x00, y11 = x00;

#define STAGE_L3(nb, k0) \
    gl_lds16(g0 + (k0), &LS[nb][0][w * 512]); \
    gl_lds16(g0 + (k0) + 32 * 512, &LS[nb][0][w * 512 + 2048]); \
    gl_lds16(g1 + (k0), &LS[nb][1][w * 512]); \
    gl_lds16(g1 + (k0) + 32 * 512, &LS[nb][1][w * 512 + 2048]); \
    gl_lds16(g2 + (k0), &LS[nb][2][w * 512]); \
    gl_lds16(g2 + (k0) + 32 * 512, &LS[nb][2][w * 512 + 2048]); \
    gl_lds16(g3 + (k0), &LS[nb][3][w * 512]); \
    gl_lds16(g3 + (k0) + 32 * 512, &LS[nb][3][w * 512 + 2048]);

    STAGE_L3(0, 0)
    __syncthreads();

    for (int step = 0; step < 8; ++step) {
        int buf = step & 1;
        if (step < 7) { STAGE_L3(buf ^ 1, (step + 1) * 64) }
#pragma unroll
        for (int ks = 0; ks < 2; ++ks) {
            int j = lc + 4 * ks;
            f16x8 s0 = *(const f16x8*)&LS[buf][0][FOFF(rA0, j)];
            f16x8 s1 = *(const f16x8*)&LS[buf][0][FOFF(rA1, j)];
            f16x8 p0 = *(const f16x8*)&LS[buf][2][FOFF(rB0, j)];
            f16x8 p1 = *(const f16x8*)&LS[buf][2][FOFF(rB1, j)];
            x00 = MFMA16(s0, p0, x00);
            x01 = MFMA16(s0, p1, x01);
            x10 = MFMA16(s1, p0, x10);
            x11 = MFMA16(s1, p1, x11);
            f16x8 c0 = *(const f16x8*)&LS[buf][1][FOFF(rA0, j)];
            f16x8 c1 = *(const f16x8*)&LS[buf][1][FOFF(rA1, j)];
            f16x8 q0 = *(const f16x8*)&LS[buf][3][FOFF(rB0, j)];
            f16x8 q1 = *(const f16x8*)&LS[buf][3][FOFF(rB1, j)];
            y00 = MFMA16(c0, q0, y00);
            y01 = MFMA16(c0, q1, y01);
            y10 = MFMA16(c1, q0, y10);
            y11 = MFMA16(c1, q1, y11);
        }
        __syncthreads();
    }
#undef STAGE_L3

    int crow = m0 + wr * 32 + lc * 4;   // v
    int ccol = n0 + wc * 32 + lr;       // u
    const f32x4* xs[2][2] = {{&x00, &x01}, {&x10, &x11}};
    const f32x4* ys[2][2] = {{&y00, &y01}, {&y10, &y11}};
#pragma unroll
    for (int q = 0; q < 2; ++q)
#pragma unroll
        for (int pp = 0; pp < 2; ++pp) {
            int u = ccol + pp * 16;
            float eu = (u ? 2.0f : 1.0f) * kInvHW;
#pragma unroll
            for (int rr = 0; rr < 4; ++rr) {
                int v = crow + q * 16 + rr;
                float gx = (*xs[q][pp])[rr];
                float gy = (*ys[q][pp])[rr];
                float num = kPiOver512 * ((float)v * gx + (float)u * gy);
                float den = 1e-10f - kPi2Norm * (float)(u * u + v * v);
                float eps = (v ? 2.0f : 1.0f) * eu;
                hst(eps * num / den, o + v * 512 + u);
            }
        }
}

// ------- d = s-t (nat + T, fp16) + partials; z==6 builds row-major tables ---
__global__ __launch_bounds__(256) void diff_split_tab(
    const float* __restrict__ s, const float* __restrict__ t, const float* __restrict__ m,
    short* __restrict__ dn, short* __restrict__ dt,
    short* __restrict__ Mc, short* __restrict__ Ms,
    short* __restrict__ McT, short* __restrict__ GT,
    float* __restrict__ mt, float* __restrict__ mi)
{
    int z = blockIdx.z;
    if (z == 6) {
        int bid = blockIdx.y * 16 + blockIdx.x;   // 0..255
        int base = (bid * 256 + threadIdx.x) * 4;
#pragma unroll
        for (int e = 0; e < 4; ++e) {
            int idx = base + e;
            int a = idx >> 9, b = idx & 511;
            int p1 = (a * (2 * b + 1)) & 2047;
            float s1, c1; sincosf((float)p1 * (kPi / 1024.0f), &s1, &c1);
            hst(c1, Mc + idx);
            hst(s1, Ms + idx);
            int p2 = (b * (2 * a + 1)) & 2047;
            float s2, c2; sincosf((float)p2 * (kPi / 1024.0f), &s2, &c2);
            hst(c2, McT + idx);
            float g = (kPi / 1024.0f) * (hfun(a + b + 1) + hfun(a - b));
            hst(g, GT + idx);
        }
        return;
    }

    __shared__ float tile[32][33];
    __shared__ float red[512];
    const float* sz = s + (size_t)z * CH;
    const float* tz = t + (size_t)z * CH;
    const float* mz = m + (size_t)z * CH;
    short* nh = dn + (size_t)z * CH;
    short* th = dt + (size_t)z * CH;
    int bx = blockIdx.x * 32, by = blockIdx.y * 32;
    int tx = threadIdx.x & 31, ty = threadIdx.x >> 5;
    float accT = 0.f, accI = 0.f;
    for (int r = ty; r < 32; r += 8) {
        int idx = (by + r) * 512 + bx + tx;
        float tv = tz[idx];
        float d = sz[idx] - tv;
        tile[r][tx] = d;
        hst(d, nh + idx);
        accT += tv;
        if (z < 3) accI += 1.0f - mz[idx];
    }
    __syncthreads();
    for (int r = ty; r < 32; r += 8) {
        hst(tile[tx][r], th + (bx + r) * 512 + by + tx);
    }
    int tid = threadIdx.x;
    red[tid] = accT; red[256 + tid] = accI;
    __syncthreads();
    for (int s2 = 128; s2 > 0; s2 >>= 1) {
        if (tid < s2) { red[tid] += red[tid + s2]; red[256 + tid] += red[256 + tid + s2]; }
        __syncthreads();
    }
    if (tid == 0) {
        int tileid = blockIdx.y * 16 + blockIdx.x;
        mt[z * 256 + tileid] = red[0];
        if (z < 3) mi[z * 256 + tileid] = red[256];
    }
}

// ---------------- final: out = t + U + shift[z] -----------------------------
__global__ __launch_bounds__(256) void final_out(
    const float* __restrict__ t, const float* __restrict__ U,
    const float* __restrict__ part, float* __restrict__ out)
{
    __shared__ float mtv[6], wmuv[3];
    int tid = threadIdx.x;
    if (tid < 6) {
        float s2 = 0.f;
        for (int k = 0; k < 256; ++k) s2 += part[tid * 256 + k];
        mtv[tid] = s2 * (1.0f / (float)CH);
    }
    if (tid >= 8 && tid < 11) {
        int c = tid - 8;
        float si = 0.f, su = 0.f;
        for (int k = 0; k < 256; ++k) si += part[1536 + c * 256 + k];
        for (int k = 0; k < 64; ++k) su += part[2304 + c * 64 + k];
        wmuv[c] = su / si;
    }
    __syncthreads();
    int n4 = NTOT / 4;
    for (int i = blockIdx.x * blockDim.x + tid; i < n4; i += gridDim.x * blockDim.x) {
        int z = i >> 16;
        int c = z % 3;
        float sh = -mtv[z] + mtv[c] - wmuv[c];
        float4 tv = ((const float4*)t)[i];
        float4 uv = ((const float4*)U)[i];
        ((float4*)out)[i] = make_float4(tv.x + uv.x + sh, tv.y + uv.y + sh,
                                        tv.z + uv.z + sh, tv.w + uv.w + sh);
    }
}

extern "C" void kernel_launch(void* const* d_in, const int* in_sizes, int n_in,
                              void* d_out, int out_size, void* d_ws, size_t ws_size,
                              hipStream_t stream) {
    const float* t = (const float*)d_in[0];
    const float* s = (const float*)d_in[1];
    const float* m = (const float*)d_in[2];
    float* out = (float*)d_out;
    float* F = (float*)d_ws;
    if (ws_size < (size_t)(21 * CH + 4096) * sizeof(float)) return;

    // row-major fp16 tables: 4 x CH = F[0 .. 2CH)
    short* T = (short*)F;
    short *Mc = T, *Ms = T + (size_t)CH, *McT = T + 2 * (size_t)CH, *GT = T + 3 * (size_t)CH;
    // four fp16 banks, 6CH each (3CH floats)
    short* A_ = (short*)(F + 2  * (size_t)CH);
    short* B_ = (short*)(F + 5  * (size_t)CH);
    short* C_ = (short*)(F + 8  * (size_t)CH);
    short* D_ = (short*)(F + 11 * (size_t)CH);
    float* F0  = F + 14 * (size_t)CH;    // 6 CH f32 (U)
    float* part = F + 20 * (size_t)CH;   // partials

    // d = s-t -> A (nat), B (transposed); partials; z==6: tables
    diff_split_tab<<<dim3(16, 16, 7), 256, 0, stream>>>(s, t, m, A_, B_,
                                                        Mc, Ms, McT, GT,
                                                        part, part + 1536);

    // L1: gx = d~GT, gyT = dT~GT + mask(+T) -> uxT (C), uyT (D)
    gemm_l1<<<dim3(8, 8, 12), 256, 0, stream>>>(A_, B_, GT, m, C_, D_);

    // L2: P = Mc~uxT -> A ; Q = Ms~uyT -> B
    gemm_tn<1><<<dim3(8, 8, 12), 256, 0, stream>>>(
        Mc, 0, C_, CH, nullptr, A_, CH,
        Ms, 0, D_, CH, nullptr, B_, CH, 6, nullptr, nullptr);

    // L3: GxT = Ms~P & GyT = Mc~Q + napply -> npT (C)
    gemm_l3<<<dim3(8, 8, 6), 256, 0, stream>>>(Ms, Mc, A_, B_, C_);

    // L4: R = McT~npT -> D
    gemm_tn<1><<<dim3(8, 8, 6), 256, 0, stream>>>(
        McT, 0, C_, CH, nullptr, D_, CH,
        McT, 0, C_, CH, nullptr, D_, CH, 6, nullptr, nullptr);

    // L5: U = R~McT -> F0 + masked-dot partials
    gemm_tn<2><<<dim3(8, 8, 6), 256, 0, stream>>>(
        D_, CH, McT, 0, F0, nullptr, CH,
        D_, CH, McT, 0, F0, nullptr, CH, 6, m, part + 2304);

    // out = t + U + shift
    final_out<<<768, 256, 0, stream>>>(t, F0, part, out);
}

// Round 13
// 64.067 us; speedup vs baseline: 1.1267x; 1.0099x over previous
//
#include <hip/hip_runtime.h>

// Poisson composition via real DCT/DST algebra on matrix cores, single-fp16
// MFMA (f32 accumulate). 7 launches. Round-8 structure (both operands
// LDS-staged, BK=64 dbuf, XCD-chunked swizzle) + fp16 U (L5 out / final in).
//   logical = (wgid%8)*(nwg/8) + wgid/8  -> each XCD owns contiguous slices;
//   panel re-reads become XCD-local L2 hits.
// Chain (TN GEMMs, C[m][n] = sum_k A[m][k]*Bt[n][k], fp16 operands):
//   d=s-t (nat->A, T->B; z==6 builds tables) ;
//   L1: gx=d~GT, gyT=dT~GT + mask(+T) -> uxT(C), uyT(D)
//   L2: P=Mc~uxT -> A, Q=Ms~uyT -> B
//   L3: GxT=Ms~P & GyT=Mc~Q + napply -> npT(C)
//   L4: R=McT~npT -> D ; L5: U=R~McT -> A fp16 (+ masked-dot partials)
//   final_out: out = t + U + shift[z].

#define CH 262144   // 512*512
#define NCH 6
#define NTOT (NCH*CH)

typedef _Float16 f16x8 __attribute__((ext_vector_type(8)));
typedef float f32x4  __attribute__((ext_vector_type(4)));

static constexpr float kPi        = 3.14159265358979323846f;
static constexpr float kPiOver512 = 0.006135923151542565f;   // pi/512
static constexpr float kPi2Norm   = 3.7649933338155804e-05f; // pi^2/512^2
static constexpr float kInvHW     = 3.814697265625e-06f;     // 1/512^2

__device__ __forceinline__ void hst(float v, short* p) {
    *reinterpret_cast<_Float16*>(p) = (_Float16)v;
}
__device__ __forceinline__ float hld(const short* p) {
    return (float)*reinterpret_cast<const _Float16*>(p);
}

__device__ __forceinline__ float hfun(int k) {
    if (k == 0) return 0.f;
    float sgn = 1.f;
    if (k < 0) { k = -k; sgn = -1.f; }
    if (k > 512) { k = 1024 - k; sgn = -sgn; }
    float sv, cv;
    sincosf((float)k * (kPi / 1024.0f), &sv, &cv);
    float v = cv / sv;
    if (k & 1) v = -v;
    return sgn * v;
}

// XCD-chunked swizzle: original wgid w lands on XCD w%8; give XCD k the
// contiguous logical chunk [k*nwg/8, (k+1)*nwg/8). Requires nwg % 8 == 0.
__device__ __forceinline__ void xcd_remap(int& bx, int& by, int& bz) {
    int nx = gridDim.x, ny = gridDim.y;
    int nwg = nx * ny * gridDim.z;
    int w = blockIdx.x + nx * (blockIdx.y + ny * blockIdx.z);
    int s = (w & 7) * (nwg >> 3) + (w >> 3);
    bx = s % nx; s /= nx;
    by = s % ny;
    bz = s / ny;
}

// ---------------- GEMM machinery (BK=64, dbuf LDS both operands) ------------
__device__ __forceinline__ void gl_lds16(const short* g, const short* l) {
    __builtin_amdgcn_global_load_lds(
        (const __attribute__((address_space(1))) void*)g,
        (__attribute__((address_space(3))) void*)l, 16, 0, 0);
}

// LDS tile: 64 rows x 64 k fp16 = 8 KB. Row r, slot s holds global chunk
// s ^ (r&7). Frag read offset for (row r, logical kchunk j):
#define FOFF(r, j) (((r) << 6) + 8 * ((j) ^ ((r) & 7)))
#define MFMA16(a, b, c) __builtin_amdgcn_mfma_f32_16x16x32_f16(a, b, c, 0, 0, 0)

// OM: 1 = fp16 out; 2 = fp16 out + masked-dot partials
template<int OM>
__global__ __launch_bounds__(256) void gemm_tn(
    const short* __restrict__ A0, int sA0, const short* __restrict__ B0, int sB0,
    short* __restrict__ O0, int sC0,
    const short* __restrict__ A1, int sA1, const short* __restrict__ B1, int sB1,
    short* __restrict__ O1, int sC1,
    int zsplit, const float* __restrict__ msk, float* __restrict__ redp)
{
    __shared__ short LS[2][2][4096];   // [buf][A,B][64x64 fp16]
    int bx, by, z;
    xcd_remap(bx, by, z);
    const short *A, *B; short* O;
    if (z < zsplit) {
        A = A0 + (size_t)z * sA0; B = B0 + (size_t)z * sB0;
        O = O0 + (size_t)z * sC0;
    } else {
        int zz = z - zsplit;
        A = A1 + (size_t)zz * sA1; B = B1 + (size_t)zz * sB1;
        O = O1 + (size_t)zz * sC1;
    }
    int tid = threadIdx.x;
    int l = tid & 63, w = tid >> 6;
    int m0 = by * 64, n0 = bx * 64;

    int srow = w * 8 + (l >> 3);
    int skc  = (l & 7) ^ ((l >> 3) & 7);
    const short* gA = A + (size_t)(m0 + srow) * 512 + 8 * skc;
    const short* gB = B + (size_t)(n0 + srow) * 512 + 8 * skc;

    int wr = w >> 1, wc = w & 1;
    int lr = l & 15, lc = l >> 4;
    int rA0 = wr * 32 + lr, rA1 = rA0 + 16;
    int rB0 = wc * 32 + lr, rB1 = rB0 + 16;

    f32x4 a00 = {0,0,0,0}, a01 = a00, a10 = a00, a11 = a00;

#define STAGE_AB(nb, k0) \
    gl_lds16(gA + (k0), &LS[nb][0][w * 512]); \
    gl_lds16(gA + (k0) + 32 * 512, &LS[nb][0][w * 512 + 2048]); \
    gl_lds16(gB + (k0), &LS[nb][1][w * 512]); \
    gl_lds16(gB + (k0) + 32 * 512, &LS[nb][1][w * 512 + 2048]);

    STAGE_AB(0, 0)
    __syncthreads();

    for (int step = 0; step < 8; ++step) {
        int buf = step & 1;
        if (step < 7) { STAGE_AB(buf ^ 1, (step + 1) * 64) }
#pragma unroll
        for (int ks = 0; ks < 2; ++ks) {
            int j = lc + 4 * ks;
            f16x8 va0 = *(const f16x8*)&LS[buf][0][FOFF(rA0, j)];
            f16x8 va1 = *(const f16x8*)&LS[buf][0][FOFF(rA1, j)];
            f16x8 vb0 = *(const f16x8*)&LS[buf][1][FOFF(rB0, j)];
            f16x8 vb1 = *(const f16x8*)&LS[buf][1][FOFF(rB1, j)];
            a00 = MFMA16(va0, vb0, a00);
            a01 = MFMA16(va0, vb1, a01);
            a10 = MFMA16(va1, vb0, a10);
            a11 = MFMA16(va1, vb1, a11);
        }
        __syncthreads();
    }
#undef STAGE_AB

    int crow = m0 + wr * 32 + lc * 4;
    int ccol = n0 + wc * 32 + lr;
    const f32x4* accs[2][2] = {{&a00, &a01}, {&a10, &a11}};
    float lsum = 0.f;
#pragma unroll
    for (int q = 0; q < 2; ++q)
#pragma unroll
        for (int pp = 0; pp < 2; ++pp)
#pragma unroll
            for (int rr = 0; rr < 4; ++rr) {
                int idx = (crow + q * 16 + rr) * 512 + ccol + pp * 16;
                float v = (*accs[q][pp])[rr];
                hst(v, O + idx);
                if (OM == 2)
                    lsum += v * (1.0f - msk[(size_t)z * CH + idx]);
            }
    if (OM == 2) {
        float* red = (float*)LS;
        red[tid] = lsum;
        __syncthreads();
        for (int s2 = 128; s2 > 0; s2 >>= 1) {
            if (tid < s2) red[tid] += red[tid + s2];
            __syncthreads();
        }
        if (tid == 0) redp[z * 64 + by * 8 + bx] = red[0];
    }
}

// ---------------- L1 fused: gradients + mask + transpose ----------------
__global__ __launch_bounds__(256) void gemm_l1(
    const short* __restrict__ dn, const short* __restrict__ dt,
    const short* __restrict__ GT, const float* __restrict__ msk,
    short* __restrict__ C_, short* __restrict__ D_)
{
    __shared__ short LS[2][2][4096];
    int bx, by, z;
    xcd_remap(bx, by, z);
    bool gxp = z < 6;
    int zz = gxp ? z : z - 6;
    const short* A = (gxp ? dn : dt) + (size_t)zz * CH;
    const float* mz = msk + (size_t)zz * CH;

    int tid = threadIdx.x;
    int l = tid & 63, w = tid >> 6;
    int m0 = by * 64, n0 = bx * 64;

    int srow = w * 8 + (l >> 3);
    int skc  = (l & 7) ^ ((l >> 3) & 7);
    const short* gA = A + (size_t)(m0 + srow) * 512 + 8 * skc;
    const short* gB = GT + (size_t)(n0 + srow) * 512 + 8 * skc;

    int wr = w >> 1, wc = w & 1;
    int lr = l & 15, lc = l >> 4;
    int rA0 = wr * 32 + lr, rA1 = rA0 + 16;
    int rB0 = wc * 32 + lr, rB1 = rB0 + 16;

    f32x4 a00 = {0,0,0,0}, a01 = a00, a10 = a00, a11 = a00;

#define STAGE_AB(nb, k0) \
    gl_lds16(gA + (k0), &LS[nb][0][w * 512]); \
    gl_lds16(gA + (k0) + 32 * 512, &LS[nb][0][w * 512 + 2048]); \
    gl_lds16(gB + (k0), &LS[nb][1][w * 512]); \
    gl_lds16(gB + (k0) + 32 * 512, &LS[nb][1][w * 512 + 2048]);

    STAGE_AB(0, 0)
    __syncthreads();

    for (int step = 0; step < 8; ++step) {
        int buf = step & 1;
        if (step < 7) { STAGE_AB(buf ^ 1, (step + 1) * 64) }
#pragma unroll
        for (int ks = 0; ks < 2; ++ks) {
            int j = lc + 4 * ks;
            f16x8 va0 = *(const f16x8*)&LS[buf][0][FOFF(rA0, j)];
            f16x8 va1 = *(const f16x8*)&LS[buf][0][FOFF(rA1, j)];
            f16x8 vb0 = *(const f16x8*)&LS[buf][1][FOFF(rB0, j)];
            f16x8 vb1 = *(const f16x8*)&LS[buf][1][FOFF(rB1, j)];
            a00 = MFMA16(va0, vb0, a00);
            a01 = MFMA16(va0, vb1, a01);
            a10 = MFMA16(va1, vb0, a10);
            a11 = MFMA16(va1, vb1, a11);
        }
        __syncthreads();
    }
#undef STAGE_AB

    const f32x4* accs[2][2] = {{&a00, &a01}, {&a10, &a11}};
    float* tile = (float*)LS;   // 64x65 floats = 16640 B

    if (gxp) {
        short* o = C_ + (size_t)zz * CH;
#pragma unroll
        for (int q = 0; q < 2; ++q)
#pragma unroll
            for (int pp = 0; pp < 2; ++pp)
#pragma unroll
                for (int rr = 0; rr < 4; ++rr) {
                    int r = wr * 32 + lc * 4 + q * 16 + rr;
                    int c = wc * 32 + pp * 16 + lr;
                    float v = (*accs[q][pp])[rr] * mz[(size_t)(m0 + r) * 512 + n0 + c];
                    tile[c * 65 + r] = v;
                }
        __syncthreads();
#pragma unroll
        for (int pass = 0; pass < 16; ++pass) {
            int jj = pass * 4 + (tid >> 6);
            int ii = tid & 63;
            hst(tile[jj * 65 + ii], o + (n0 + jj) * 512 + m0 + ii);
        }
    } else {
        short* o = D_ + (size_t)zz * CH;
#pragma unroll
        for (int pass = 0; pass < 16; ++pass) {
            int ii = pass * 4 + (tid >> 6);
            int jj = tid & 63;
            tile[jj * 65 + ii] = mz[(size_t)(n0 + ii) * 512 + m0 + jj];
        }
        __syncthreads();
#pragma unroll
        for (int q = 0; q < 2; ++q)
#pragma unroll
            for (int pp = 0; pp < 2; ++pp)
#pragma unroll
                for (int rr = 0; rr < 4; ++rr) {
                    int r = wr * 32 + lc * 4 + q * 16 + rr;
                    int c = wc * 32 + pp * 16 + lr;
                    float v = (*accs[q][pp])[rr] * tile[r * 65 + c];
                    hst(v, o + (m0 + r) * 512 + n0 + c);
                }
    }
}

// ---------------- L3 fused: GxT & GyT + napply epilogue ----------------
__global__ __launch_bounds__(256) void gemm_l3(
    const short* __restrict__ Ms, const short* __restrict__ Mc,
    const short* __restrict__ P, const short* __restrict__ Q,
    short* __restrict__ O_)
{
    __shared__ short LS[2][4][4096];   // Ms, Mc, P, Q
    int bx, by, z;
    xcd_remap(bx, by, z);
    const short* pz = P + (size_t)z * CH;
    const short* qz = Q + (size_t)z * CH;
    short* o = O_ + (size_t)z * CH;

    int tid = threadIdx.x;
    int l = tid & 63, w = tid >> 6;
    int m0 = by * 64, n0 = bx * 64;

    int srow = w * 8 + (l >> 3);
    int skc  = (l & 7) ^ ((l >> 3) & 7);
    size_t ga = (size_t)(m0 + srow) * 512 + 8 * skc;
    size_t gb = (size_t)(n0 + srow) * 512 + 8 * skc;
    const short* g0 = Ms + ga;
    const short* g1 = Mc + ga;
    const short* g2 = pz + gb;
    const short* g3 = qz + gb;

    int wr = w >> 1, wc = w & 1;
    int lr = l & 15, lc = l >> 4;
    int rA0 = wr * 32 + lr, rA1 = rA0 + 16;
    int rB0 = wc * 32 + lr, rB1 = rB0 + 16;

    f32x4 x00 = {0,0,0,0}, x01 = x00, x10 = x00, x11 = x00;
    f32x4 y00 = x00, y01 = x00, y10 = x00, y11 = x00;

#define STAGE_L3(nb, k0) \
    gl_lds16(g0 + (k0), &LS[nb][0][w * 512]); \
    gl_lds16(g0 + (k0) + 32 * 512, &LS[nb][0][w * 512 + 2048]); \
    gl_lds16(g1 + (k0), &LS[nb][1][w * 512]); \
    gl_lds16(g1 + (k0) + 32 * 512, &LS[nb][1][w * 512 + 2048]); \
    gl_lds16(g2 + (k0), &LS[nb][2][w * 512]); \
    gl_lds16(g2 + (k0) + 32 * 512, &LS[nb][2][w * 512 + 2048]); \
    gl_lds16(g3 + (k0), &LS[nb][3][w * 512]); \
    gl_lds16(g3 + (k0) + 32 * 512, &LS[nb][3][w * 512 + 2048]);

    STAGE_L3(0, 0)
    __syncthreads();

    for (int step = 0; step < 8; ++step) {
        int buf = step & 1;
        if (step < 7) { STAGE_L3(buf ^ 1, (step + 1) * 64) }
#pragma unroll
        for (int ks = 0; ks < 2; ++ks) {
            int j = lc + 4 * ks;
            f16x8 s0 = *(const f16x8*)&LS[buf][0][FOFF(rA0, j)];
            f16x8 s1 = *(const f16x8*)&LS[buf][0][FOFF(rA1, j)];
            f16x8 p0 = *(const f16x8*)&LS[buf][2][FOFF(rB0, j)];
            f16x8 p1 = *(const f16x8*)&LS[buf][2][FOFF(rB1, j)];
            x00 = MFMA16(s0, p0, x00);
            x01 = MFMA16(s0, p1, x01);
            x10 = MFMA16(s1, p0, x10);
            x11 = MFMA16(s1, p1, x11);
            f16x8 c0 = *(const f16x8*)&LS[buf][1][FOFF(rA0, j)];
            f16x8 c1 = *(const f16x8*)&LS[buf][1][FOFF(rA1, j)];
            f16x8 q0 = *(const f16x8*)&LS[buf][3][FOFF(rB0, j)];
            f16x8 q1 = *(const f16x8*)&LS[buf][3][FOFF(rB1, j)];
            y00 = MFMA16(c0, q0, y00);
            y01 = MFMA16(c0, q1, y01);
            y10 = MFMA16(c1, q0, y10);
            y11 = MFMA16(c1, q1, y11);
        }
        __syncthreads();
    }
#undef STAGE_L3

    int crow = m0 + wr * 32 + lc * 4;   // v
    int ccol = n0 + wc * 32 + lr;       // u
    const f32x4* xs[2][2] = {{&x00, &x01}, {&x10, &x11}};
    const f32x4* ys[2][2] = {{&y00, &y01}, {&y10, &y11}};
#pragma unroll
    for (int q = 0; q < 2; ++q)
#pragma unroll
        for (int pp = 0; pp < 2; ++pp) {
            int u = ccol + pp * 16;
            float eu = (u ? 2.0f : 1.0f) * kInvHW;
#pragma unroll
            for (int rr = 0; rr < 4; ++rr) {
                int v = crow + q * 16 + rr;
                float gx = (*xs[q][pp])[rr];
                float gy = (*ys[q][pp])[rr];
                float num = kPiOver512 * ((float)v * gx + (float)u * gy);
                float den = 1e-10f - kPi2Norm * (float)(u * u + v * v);
                float eps = (v ? 2.0f : 1.0f) * eu;
                hst(eps * num / den, o + v * 512 + u);
            }
        }
}

// ------- d = s-t (nat + T, fp16) + partials; z==6 builds row-major tables ---
__global__ __launch_bounds__(256) void diff_split_tab(
    const float* __restrict__ s, const float* __restrict__ t, const float* __restrict__ m,
    short* __restrict__ dn, short* __restrict__ dt,
    short* __restrict__ Mc, short* __restrict__ Ms,
    short* __restrict__ McT, short* __restrict__ GT,
    float* __restrict__ mt, float* __restrict__ mi)
{
    int z = blockIdx.z;
    if (z == 6) {
        int bid = blockIdx.y * 16 + blockIdx.x;   // 0..255
        int base = (bid * 256 + threadIdx.x) * 4;
#pragma unroll
        for (int e = 0; e < 4; ++e) {
            int idx = base + e;
            int a = idx >> 9, b = idx & 511;
            int p1 = (a * (2 * b + 1)) & 2047;
            float s1, c1; sincosf((float)p1 * (kPi / 1024.0f), &s1, &c1);
            hst(c1, Mc + idx);
            hst(s1, Ms + idx);
            int p2 = (b * (2 * a + 1)) & 2047;
            float s2, c2; sincosf((float)p2 * (kPi / 1024.0f), &s2, &c2);
            hst(c2, McT + idx);
            float g = (kPi / 1024.0f) * (hfun(a + b + 1) + hfun(a - b));
            hst(g, GT + idx);
        }
        return;
    }

    __shared__ float tile[32][33];
    __shared__ float red[512];
    const float* sz = s + (size_t)z * CH;
    const float* tz = t + (size_t)z * CH;
    const float* mz = m + (size_t)z * CH;
    short* nh = dn + (size_t)z * CH;
    short* th = dt + (size_t)z * CH;
    int bx = blockIdx.x * 32, by = blockIdx.y * 32;
    int tx = threadIdx.x & 31, ty = threadIdx.x >> 5;
    float accT = 0.f, accI = 0.f;
    for (int r = ty; r < 32; r += 8) {
        int idx = (by + r) * 512 + bx + tx;
        float tv = tz[idx];
        float d = sz[idx] - tv;
        tile[r][tx] = d;
        hst(d, nh + idx);
        accT += tv;
        if (z < 3) accI += 1.0f - mz[idx];
    }
    __syncthreads();
    for (int r = ty; r < 32; r += 8) {
        hst(tile[tx][r], th + (bx + r) * 512 + by + tx);
    }
    int tid = threadIdx.x;
    red[tid] = accT; red[256 + tid] = accI;
    __syncthreads();
    for (int s2 = 128; s2 > 0; s2 >>= 1) {
        if (tid < s2) { red[tid] += red[tid + s2]; red[256 + tid] += red[256 + tid + s2]; }
        __syncthreads();
    }
    if (tid == 0) {
        int tileid = blockIdx.y * 16 + blockIdx.x;
        mt[z * 256 + tileid] = red[0];
        if (z < 3) mi[z * 256 + tileid] = red[256];
    }
}

// ---------------- final: out = t + U(fp16) + shift[z] -----------------------
__global__ __launch_bounds__(256) void final_out(
    const float* __restrict__ t, const short* __restrict__ U16,
    const float* __restrict__ part, float* __restrict__ out)
{
    __shared__ float mtv[6], wmuv[3];
    int tid = threadIdx.x;
    if (tid < 6) {
        float s2 = 0.f;
        for (int k = 0; k < 256; ++k) s2 += part[tid * 256 + k];
        mtv[tid] = s2 * (1.0f / (float)CH);
    }
    if (tid >= 8 && tid < 11) {
        int c = tid - 8;
        float si = 0.f, su = 0.f;
        for (int k = 0; k < 256; ++k) si += part[1536 + c * 256 + k];
        for (int k = 0; k < 64; ++k) su += part[2304 + c * 64 + k];
        wmuv[c] = su / si;
    }
    __syncthreads();
    int n4 = NTOT / 4;
    for (int i = blockIdx.x * blockDim.x + tid; i < n4; i += gridDim.x * blockDim.x) {
        int z = i >> 16;
        int c = z % 3;
        float sh = -mtv[z] + mtv[c] - wmuv[c];
        float4 tv = ((const float4*)t)[i];
        short4 us = ((const short4*)U16)[i];
        float u0 = hld(&us.x), u1 = hld(&us.y), u2 = hld(&us.z), u3 = hld(&us.w);
        ((float4*)out)[i] = make_float4(tv.x + u0 + sh, tv.y + u1 + sh,
                                        tv.z + u2 + sh, tv.w + u3 + sh);
    }
}

extern "C" void kernel_launch(void* const* d_in, const int* in_sizes, int n_in,
                              void* d_out, int out_size, void* d_ws, size_t ws_size,
                              hipStream_t stream) {
    const float* t = (const float*)d_in[0];
    const float* s = (const float*)d_in[1];
    const float* m = (const float*)d_in[2];
    float* out = (float*)d_out;
    float* F = (float*)d_ws;
    if (ws_size < (size_t)(21 * CH + 4096) * sizeof(float)) return;

    // row-major fp16 tables: 4 x CH = F[0 .. 2CH)
    short* T = (short*)F;
    short *Mc = T, *Ms = T + (size_t)CH, *McT = T + 2 * (size_t)CH, *GT = T + 3 * (size_t)CH;
    // four fp16 banks, 6CH each (3CH floats)
    short* A_ = (short*)(F + 2  * (size_t)CH);
    short* B_ = (short*)(F + 5  * (size_t)CH);
    short* C_ = (short*)(F + 8  * (size_t)CH);
    short* D_ = (short*)(F + 11 * (size_t)CH);
    float* part = F + 20 * (size_t)CH;   // partials

    // d = s-t -> A (nat), B (transposed); partials; z==6: tables
    diff_split_tab<<<dim3(16, 16, 7), 256, 0, stream>>>(s, t, m, A_, B_,
                                                        Mc, Ms, McT, GT,
                                                        part, part + 1536);

    // L1: gx = d~GT, gyT = dT~GT + mask(+T) -> uxT (C), uyT (D)
    gemm_l1<<<dim3(8, 8, 12), 256, 0, stream>>>(A_, B_, GT, m, C_, D_);

    // L2: P = Mc~uxT -> A ; Q = Ms~uyT -> B
    gemm_tn<1><<<dim3(8, 8, 12), 256, 0, stream>>>(
        Mc, 0, C_, CH, A_, CH,
        Ms, 0, D_, CH, B_, CH, 6, nullptr, nullptr);

    // L3: GxT = Ms~P & GyT = Mc~Q + napply -> npT (C)
    gemm_l3<<<dim3(8, 8, 6), 256, 0, stream>>>(Ms, Mc, A_, B_, C_);

    // L4: R = McT~npT -> D
    gemm_tn<1><<<dim3(8, 8, 6), 256, 0, stream>>>(
        McT, 0, C_, CH, D_, CH,
        McT, 0, C_, CH, D_, CH, 6, nullptr, nullptr);

    // L5: U = R~McT -> A (fp16) + masked-dot partials
    gemm_tn<2><<<dim3(8, 8, 6), 256, 0, stream>>>(
        D_, CH, McT, 0, A_, CH,
        D_, CH, McT, 0, A_, CH, 6, m, part + 2304);

    // out = t + U + shift
    final_out<<<768, 256, 0, stream>>>(t, A_, part, out);
}